// Round 3
// baseline (766.771 us; speedup 1.0000x reference)
//
#include <hip/hip_runtime.h>

#define B_N 16384
#define D_K 512
#define C_N 1000
#define CP 1024
#define M_N 8
#define GAP_EPS 2e-4f
#define NT 48   // virtual K' = 1536 = 48 K-tiles of 32

typedef __attribute__((ext_vector_type(8))) short bf16x8;
typedef __attribute__((ext_vector_type(4))) float f32x4;

typedef const __attribute__((address_space(1))) unsigned int* gptr_t;
typedef __attribute__((address_space(3))) unsigned int* lptr_t;

__device__ __forceinline__ void gload16(const void* g, void* l) {
    __builtin_amdgcn_global_load_lds((gptr_t)g, (lptr_t)l, 16, 0, 0);
}

#define BAR()        asm volatile("s_barrier" ::: "memory")
#define WAIT_LGKM0() asm volatile("s_waitcnt lgkmcnt(0)" ::: "memory")
#define WAIT_VM8()   asm volatile("s_waitcnt vmcnt(8)" ::: "memory")
#define WAIT_VM4()   asm volatile("s_waitcnt vmcnt(4)" ::: "memory")
#define WAIT_VM0()   asm volatile("s_waitcnt vmcnt(0)" ::: "memory")
#define SCHEDB()     __builtin_amdgcn_sched_barrier(0)

__device__ __forceinline__ unsigned short bf16_rn(float f) {
    unsigned u = __float_as_uint(f);
    unsigned lsb = (u >> 16) & 1u;
    u += 0x7FFFu + lsb;
    return (unsigned short)(u >> 16);
}

__device__ __forceinline__ void split2(float f, unsigned short& h, unsigned short& l) {
    unsigned u = __float_as_uint(f) & 0xFFFF0000u;
    h = (unsigned short)(u >> 16);
    float r = f - __uint_as_float(u);
    l = bf16_rn(r);
}

// ---------------- conversion kernels ----------------

__global__ __launch_bounds__(256) void ve_conv_x(const float* __restrict__ x,
        unsigned short* __restrict__ xh, unsigned short* __restrict__ xl,
        unsigned int* __restrict__ cnt) {
    int i = blockIdx.x * 256 + threadIdx.x;
    if (i == 0) *cnt = 0u;
    float4 v = reinterpret_cast<const float4*>(x)[i];
    ushort4 h, l;
    split2(v.x, h.x, l.x); split2(v.y, h.y, l.y);
    split2(v.z, h.z, l.z); split2(v.w, h.w, l.w);
    reinterpret_cast<ushort4*>(xh)[i] = h;
    reinterpret_cast<ushort4*>(xl)[i] = l;
}

__global__ __launch_bounds__(256) void ve_conv_w(const float* __restrict__ W,
        unsigned short* __restrict__ wht, unsigned short* __restrict__ wlt) {
    __shared__ float t[64][65];
    const int m = blockIdx.z, k0 = blockIdx.y * 64, c0 = blockIdx.x * 64;
    const int tid = threadIdx.x;
#pragma unroll
    for (int p = 0; p < 16; ++p) {
        int idx = p * 256 + tid;
        int kk = idx >> 6, cc = idx & 63;
        int c = c0 + cc;
        t[kk][cc] = (c < C_N) ? W[((size_t)m * D_K + k0 + kk) * C_N + c] : 0.f;
    }
    __syncthreads();
#pragma unroll
    for (int p = 0; p < 4; ++p) {
        int idx = p * 256 + tid;
        int cc = idx >> 4, kq = idx & 15;
        ushort4 h, l;
        split2(t[kq * 4 + 0][cc], h.x, l.x);
        split2(t[kq * 4 + 1][cc], h.y, l.y);
        split2(t[kq * 4 + 2][cc], h.z, l.z);
        split2(t[kq * 4 + 3][cc], h.w, l.w);
        size_t o = ((size_t)m * CP + c0 + cc) * D_K + k0 + kq * 4;
        *reinterpret_cast<ushort4*>(wht + o) = h;
        *reinterpret_cast<ushort4*>(wlt + o) = l;
    }
}

// ---------------- pipelined 256x256 MFMA GEMM (virtual K'=1536) ----------------
// Segments: t in [0,16): xh*wh, [16,32): xh*wl, [32,48): xl*wh.
// 4 LDS buffers, stage K-tile t+3 while computing t; vmcnt(8) counted waits.

__global__ __launch_bounds__(512, 1) void ve_gemm8(
        const unsigned short* __restrict__ Xh, const unsigned short* __restrict__ Xl,
        const unsigned short* __restrict__ WhT, const unsigned short* __restrict__ WlT,
        const float* __restrict__ bias, float4* __restrict__ part) {
    __shared__ unsigned short Abuf[4][8192];   // [buf][256 rows * 32 k]
    __shared__ unsigned short Bbuf[4][8192];   // [buf][256 cols * 32 k]
    __shared__ float4 wtop[256][4];
    __shared__ float bs[256];

    const int tid = threadIdx.x;
    const int l = tid & 63, w = tid >> 6;
    const int wr = w >> 2, wc = w & 3;          // 2M x 4N waves; per-wave C = 128x64
    const int l15 = l & 15, kg8 = (l >> 4) * 8;
    const int rt = blockIdx.x, ct = blockIdx.y, mb = blockIdx.z;
    const int r0 = rt * 256, c0 = ct * 256;
    const int srow = w * 16 + (l >> 2);         // staging row within 128-row quarter
    const int schunk = (l & 3) * 8;             // staging 16B chunk within 32-k row

    if (tid < 256) {
        int c = c0 + tid;
        bs[tid] = (c < C_N) ? bias[mb * C_N + c] : -1e30f;
    }

    auto stageQ = [&](int u, int q) {
        if (u >= NT) return;
        const int cu = u & 3;
        const int kb = (u & 15) * 32;
        if (q < 2) {
            const unsigned short* Ap = (u < 32) ? Xh : Xl;
            const unsigned short* g = Ap + (size_t)(r0 + q * 128 + srow) * D_K + kb + schunk;
            gload16(g, &Abuf[cu][q * 4096 + w * 512]);
        } else {
            const unsigned short* Bp = (u >= 16 && u < 32) ? WlT : WhT;
            const unsigned short* g = Bp + ((size_t)mb * CP + c0 + (q - 2) * 128 + srow) * D_K + kb + schunk;
            gload16(g, &Bbuf[cu][(q - 2) * 4096 + w * 512]);
        }
    };

    // prologue: stage K-tiles 0,1,2 (12 loads/thread); require tile 0 landed.
#pragma unroll
    for (int u = 0; u < 3; ++u) {
        stageQ(u, 0); stageQ(u, 1); stageQ(u, 2); stageQ(u, 3);
    }
    WAIT_VM8();
    BAR();

    f32x4 acc[8][4];
#pragma unroll
    for (int i = 0; i < 8; ++i)
#pragma unroll
        for (int j = 0; j < 4; ++j) acc[i][j] = (f32x4){0.f, 0.f, 0.f, 0.f};

    for (int t = 0; t < NT; ++t) {
        const int c = t & 3;
        const unsigned short* Ab = Abuf[c];
        const unsigned short* Bb = Bbuf[c];
        bf16x8 bf[4], af[4];

        // ---------- phase 0: rows 0..63 of wave's 128 ----------
#pragma unroll
        for (int j = 0; j < 4; ++j)
            bf[j] = *reinterpret_cast<const bf16x8*>(Bb + (wc * 64 + j * 16 + l15) * 32 + kg8);
#pragma unroll
        for (int i = 0; i < 4; ++i)
            af[i] = *reinterpret_cast<const bf16x8*>(Ab + (wr * 128 + i * 16 + l15) * 32 + kg8);
        stageQ(t + 3, 0); stageQ(t + 3, 1);
        BAR();
        WAIT_LGKM0(); SCHEDB();
        __builtin_amdgcn_s_setprio(1);
#pragma unroll
        for (int i = 0; i < 4; ++i)
#pragma unroll
            for (int j = 0; j < 4; ++j)
                acc[i][j] = __builtin_amdgcn_mfma_f32_16x16x32_bf16(af[i], bf[j], acc[i][j], 0, 0, 0);
        __builtin_amdgcn_s_setprio(0);
        BAR();

        // ---------- phase 1: rows 64..127 ----------
#pragma unroll
        for (int i = 0; i < 4; ++i)
            af[i] = *reinterpret_cast<const bf16x8*>(Ab + (wr * 128 + 64 + i * 16 + l15) * 32 + kg8);
        stageQ(t + 3, 2); stageQ(t + 3, 3);
        // counted wait: guarantee tile t+1 landed; keep t+2/t+3 in flight.
        if (t + 3 < NT)      { WAIT_VM8(); }
        else if (t + 2 < NT) { WAIT_VM4(); }
        else                 { WAIT_VM0(); }
        BAR();
        WAIT_LGKM0(); SCHEDB();
        __builtin_amdgcn_s_setprio(1);
#pragma unroll
        for (int i = 0; i < 4; ++i)
#pragma unroll
            for (int j = 0; j < 4; ++j)
                acc[4 + i][j] = __builtin_amdgcn_mfma_f32_16x16x32_bf16(af[i], bf[j], acc[4 + i][j], 0, 0, 0);
        __builtin_amdgcn_s_setprio(0);
        BAR();
    }

    // ---------------- epilogue: bias + per-wave top-2 over its 64 cols ----------------
    float bsv[4]; int cg[4];
#pragma unroll
    for (int j = 0; j < 4; ++j) {
        int cl = wc * 64 + j * 16 + l15;
        bsv[j] = bs[cl];
        cg[j] = c0 + cl;
    }
#pragma unroll
    for (int i = 0; i < 8; ++i) {
#pragma unroll
        for (int reg = 0; reg < 4; ++reg) {
            float v1 = acc[i][0][reg] + bsv[0]; int i1 = cg[0];
            float v2 = -1e30f; int i2 = 0x7fffffff;
#pragma unroll
            for (int j = 1; j < 4; ++j) {
                float v = acc[i][j][reg] + bsv[j]; int cc = cg[j];
                if (v > v1 || (v == v1 && cc < i1)) { v2 = v1; i2 = i1; v1 = v; i1 = cc; }
                else if (v > v2 || (v == v2 && cc < i2)) { v2 = v; i2 = cc; }
            }
#pragma unroll
            for (int mask = 1; mask < 16; mask <<= 1) {
                float ov1 = __shfl_xor(v1, mask); int oi1 = __shfl_xor(i1, mask);
                float ov2 = __shfl_xor(v2, mask); int oi2 = __shfl_xor(i2, mask);
                if (ov1 > v1 || (ov1 == v1 && oi1 < i1)) {
                    float nv2 = v1; int ni2 = i1;
                    if (ov2 > nv2 || (ov2 == nv2 && oi2 < ni2)) { nv2 = ov2; ni2 = oi2; }
                    v1 = ov1; i1 = oi1; v2 = nv2; i2 = ni2;
                } else if (ov1 > v2 || (ov1 == v2 && oi1 < i2)) { v2 = ov1; i2 = oi1; }
            }
            if (l15 == 0) {
                int row = wr * 128 + i * 16 + (l >> 4) * 4 + reg;
                wtop[row][wc] = make_float4(v1, __int_as_float(i1), v2, __int_as_float(i2));
            }
        }
    }
    BAR();
    if (tid < 256) {
        float v1 = -1e30f; int i1 = 0x7fffffff;
        float v2 = -1e30f; int i2 = 0x7fffffff;
#pragma unroll
        for (int s = 0; s < 4; ++s) {
            float4 o = wtop[tid][s];
            float ov1 = o.x; int oi1 = __float_as_int(o.y);
            float ov2 = o.z; int oi2 = __float_as_int(o.w);
            if (ov1 > v1 || (ov1 == v1 && oi1 < i1)) {
                float nv2 = v1; int ni2 = i1;
                if (ov2 > nv2 || (ov2 == nv2 && oi2 < ni2)) { nv2 = ov2; ni2 = oi2; }
                v1 = ov1; i1 = oi1; v2 = nv2; i2 = ni2;
            } else if (ov1 > v2 || (ov1 == v2 && oi1 < i2)) { v2 = ov1; i2 = oi1; }
        }
        part[((size_t)mb * B_N + r0 + tid) * 4 + ct] =
            make_float4(v1, __int_as_float(i1), v2, __int_as_float(i2));
    }
}

// ---------------- merge 4 C-tiles, flag uncertain rows ----------------

__global__ __launch_bounds__(256) void ve_flag4(const float4* __restrict__ part,
        unsigned int* __restrict__ wout, unsigned int* __restrict__ list,
        unsigned int* __restrict__ cnt) {
    int r = blockIdx.x * 256 + threadIdx.x;
#pragma unroll
    for (int m = 0; m < M_N; ++m) {
        float v1 = -1e30f; int i1 = 0x7fffffff;
        float v2 = -1e30f; int i2 = 0x7fffffff;
#pragma unroll
        for (int t = 0; t < 4; ++t) {
            float4 o = part[((size_t)m * B_N + r) * 4 + t];
            float ov1 = o.x; int oi1 = __float_as_int(o.y);
            float ov2 = o.z; int oi2 = __float_as_int(o.w);
            if (ov1 > v1 || (ov1 == v1 && oi1 < i1)) {
                float nv2 = v1; int ni2 = i1;
                if (ov2 > nv2 || (ov2 == nv2 && oi2 < ni2)) { nv2 = ov2; ni2 = oi2; }
                v1 = ov1; i1 = oi1; v2 = nv2; i2 = ni2;
            } else if (ov1 > v2 || (ov1 == v2 && oi1 < i2)) { v2 = ov1; i2 = oi1; }
        }
        wout[m * B_N + r] = (unsigned)i1;
        if (v1 - v2 <= GAP_EPS) {
            unsigned pos = atomicAdd(cnt, 1u);
            list[pos] = (unsigned)(m * B_N + r);
        }
    }
}

// Exact fp32 serial-FMA argmax for flagged rows (numpy-matching accumulation).
__global__ __launch_bounds__(256) void ve_exact(const float* __restrict__ x,
        const float* __restrict__ W, const float* __restrict__ bias,
        const unsigned int* __restrict__ list, const unsigned int* __restrict__ cnt,
        unsigned int* __restrict__ wout) {
    __shared__ float xs[D_K];
    __shared__ float rv[4];
    __shared__ int ri[4];
    const int tid = threadIdx.x;
    const int lane = tid & 63, wv = tid >> 6;
    const unsigned n = *cnt;
    for (unsigned u = blockIdx.x; u < n; u += gridDim.x) {
        unsigned e = list[u];
        int m = (int)(e >> 14), r = (int)(e & (B_N - 1));
        __syncthreads();
        for (int i = tid; i < D_K; i += 256) xs[i] = x[(size_t)r * D_K + i];
        __syncthreads();
        float a0 = 0.f, a1 = 0.f, a2 = 0.f, a3 = 0.f;
        const int g3 = (tid < C_N - 768);
        const int c3 = g3 ? tid + 768 : tid;
        const float* wb = W + (size_t)m * D_K * C_N;
        for (int k = 0; k < D_K; ++k) {
            float xv = xs[k];
            const float* wr_ = wb + (size_t)k * C_N;
            a0 = fmaf(xv, wr_[tid], a0);
            a1 = fmaf(xv, wr_[tid + 256], a1);
            a2 = fmaf(xv, wr_[tid + 512], a2);
            a3 = fmaf(xv, wr_[c3], a3);
        }
        const float* bb = bias + m * C_N;
        float best = a0 + bb[tid]; int bi = tid;
        float v = a1 + bb[tid + 256]; if (v > best) { best = v; bi = tid + 256; }
        v = a2 + bb[tid + 512]; if (v > best) { best = v; bi = tid + 512; }
        if (g3) { v = a3 + bb[tid + 768]; if (v > best) { best = v; bi = tid + 768; } }
#pragma unroll
        for (int mask = 1; mask < 64; mask <<= 1) {
            float ov = __shfl_xor(best, mask); int oi = __shfl_xor(bi, mask);
            if (ov > best || (ov == best && oi < bi)) { best = ov; bi = oi; }
        }
        if (lane == 0) { rv[wv] = best; ri[wv] = bi; }
        __syncthreads();
        if (tid == 0) {
            for (int q = 1; q < 4; ++q)
                if (rv[q] > best || (rv[q] == best && ri[q] < bi)) { best = rv[q]; bi = ri[q]; }
            wout[e] = (unsigned)bi;
        }
    }
}

__global__ __launch_bounds__(256) void ve_zero_out(float* __restrict__ out, int n4) {
    int i = blockIdx.x * blockDim.x + threadIdx.x;
    const float4 z = make_float4(0.f, 0.f, 0.f, 0.f);
    for (; i < n4; i += gridDim.x * blockDim.x)
        reinterpret_cast<float4*>(out)[i] = z;
}

__global__ __launch_bounds__(256) void ve_vote2(const unsigned int* __restrict__ wout,
        const float* __restrict__ coefs, float* __restrict__ out) {
    int r = blockIdx.x * 256 + threadIdx.x;
#pragma unroll
    for (int m = 0; m < M_N; ++m)
        out[(size_t)r * C_N + wout[m * B_N + r]] += coefs[m] * 0.125f;
}

// ================= fallback: proven round-1 fp32 path =================

#define TM 128
#define TN 128
#define TK 32
#define CT 8

__global__ __launch_bounds__(256) void ve_gemm_argmax_fb(
        const float* __restrict__ x, const float* __restrict__ W,
        const float* __restrict__ bias, float2* __restrict__ part) {
    __shared__ float xs[TK][TM + 1];
    __shared__ float ws[TK][TN];
    const int ct = blockIdx.x, rt = blockIdx.y, m = blockIdx.z;
    const int tid = threadIdx.x;
    const int tx = tid & 15, ty = tid >> 4;
    const int r0 = rt * TM, c0 = ct * TN;
    float acc[8][8];
#pragma unroll
    for (int i = 0; i < 8; i++)
#pragma unroll
        for (int j = 0; j < 8; j++) acc[i][j] = 0.f;
    const float* xbase = x + (size_t)r0 * D_K;
    for (int kt = 0; kt < D_K; kt += TK) {
#pragma unroll
        for (int i = 0; i < 4; i++) {
            int l = tid + i * 256;
            int row = l >> 3, kq = l & 7;
            float4 v = *reinterpret_cast<const float4*>(xbase + (size_t)row * D_K + kt + kq * 4);
            int kk = kq * 4;
            xs[kk + 0][row] = v.x; xs[kk + 1][row] = v.y;
            xs[kk + 2][row] = v.z; xs[kk + 3][row] = v.w;
        }
#pragma unroll
        for (int i = 0; i < 4; i++) {
            int l = tid + i * 256;
            int kk = l >> 5, cq = l & 31;
            int c = c0 + cq * 4;
            const float* p = W + ((size_t)(m * D_K + kt + kk)) * C_N + c;
            float4 v;
            if (c + 3 < C_N) v = *reinterpret_cast<const float4*>(p);
            else {
                v.x = (c + 0 < C_N) ? p[0] : 0.f; v.y = (c + 1 < C_N) ? p[1] : 0.f;
                v.z = (c + 2 < C_N) ? p[2] : 0.f; v.w = (c + 3 < C_N) ? p[3] : 0.f;
            }
            ws[kk][cq * 4 + 0] = v.x; ws[kk][cq * 4 + 1] = v.y;
            ws[kk][cq * 4 + 2] = v.z; ws[kk][cq * 4 + 3] = v.w;
        }
        __syncthreads();
        for (int kk = 0; kk < TK; kk++) {
            float a[8], bb[8];
#pragma unroll
            for (int i = 0; i < 8; i++) a[i] = xs[kk][ty + i * 16];
#pragma unroll
            for (int j = 0; j < 8; j++) bb[j] = ws[kk][tx + j * 16];
#pragma unroll
            for (int i = 0; i < 8; i++)
#pragma unroll
                for (int j = 0; j < 8; j++) acc[i][j] += a[i] * bb[j];
        }
        __syncthreads();
    }
    const float NEG_INF = -__builtin_huge_valf();
    float bv[8]; int cv[8];
#pragma unroll
    for (int j = 0; j < 8; j++) {
        int c = c0 + tx + j * 16;
        cv[j] = c;
        bv[j] = (c < C_N) ? bias[m * C_N + c] : 0.f;
    }
#pragma unroll
    for (int i = 0; i < 8; i++) {
        int r = r0 + ty + i * 16;
        float best = NEG_INF; int bidx = 0x7fffffff;
#pragma unroll
        for (int j = 0; j < 8; j++) {
            int c = cv[j];
            float v = (c < C_N) ? (acc[i][j] + bv[j]) : NEG_INF;
            if (v > best || (v == best && c < bidx)) { best = v; bidx = c; }
        }
#pragma unroll
        for (int mask = 1; mask < 16; mask <<= 1) {
            float ov = __shfl_xor(best, mask);
            int oi = __shfl_xor(bidx, mask);
            if (ov > best || (ov == best && oi < bidx)) { best = ov; bidx = oi; }
        }
        if (tx == 0) part[((size_t)m * B_N + r) * CT + ct] = make_float2(best, __int_as_float(bidx));
    }
}

__global__ __launch_bounds__(256) void ve_vote_fb(const float2* __restrict__ part,
        const float* __restrict__ coefs, float* __restrict__ out) {
    int r = blockIdx.x * blockDim.x + threadIdx.x;
    if (r >= B_N) return;
    const float NEG_INF = -__builtin_huge_valf();
#pragma unroll
    for (int m = 0; m < M_N; m++) {
        float best = NEG_INF; int bidx = 0x7fffffff;
#pragma unroll
        for (int ct = 0; ct < CT; ct++) {
            float2 p = part[((size_t)m * B_N + r) * CT + ct];
            int oi = __float_as_int(p.y);
            if (p.x > best || (p.x == best && oi < bidx)) { best = p.x; bidx = oi; }
        }
        out[(size_t)r * C_N + bidx] += coefs[m] * 0.125f;
    }
}

// ================= launcher =================

extern "C" void kernel_launch(void* const* d_in, const int* in_sizes, int n_in,
                              void* d_out, int out_size, void* d_ws, size_t ws_size,
                              hipStream_t stream) {
    const float* x     = (const float*)d_in[0];
    const float* W     = (const float*)d_in[1];
    const float* bias  = (const float*)d_in[2];
    const float* coefs = (const float*)d_in[3];
    float* out = (float*)d_out;

    const size_t NEED = (57ull << 20) + 4096;
    if (ws_size >= NEED) {
        char* ws = (char*)d_ws;
        unsigned short* Xh   = (unsigned short*)(ws);                  // 16 MiB
        unsigned short* Xl   = (unsigned short*)(ws + (16ull << 20));  // 16 MiB
        unsigned short* WhT  = (unsigned short*)(ws + (32ull << 20));  //  8 MiB
        unsigned short* WlT  = (unsigned short*)(ws + (40ull << 20));  //  8 MiB
        float4*         part = (float4*)(ws + (48ull << 20));          //  8 MiB
        unsigned int*   wout = (unsigned int*)(ws + (56ull << 20));    // 512 KiB
        unsigned int*   list = (unsigned int*)(ws + (56ull << 20) + (512ull << 10));
        unsigned int*   cnt  = (unsigned int*)(ws + (57ull << 20));

        ve_conv_x<<<8192, 256, 0, stream>>>(x, Xh, Xl, cnt);
        ve_conv_w<<<dim3(16, 8, 8), 256, 0, stream>>>(W, WhT, WlT);
        ve_gemm8<<<dim3(64, 4, 8), 512, 0, stream>>>(Xh, Xl, WhT, WlT, bias, part);
        ve_flag4<<<64, 256, 0, stream>>>(part, wout, list, cnt);
        ve_exact<<<128, 256, 0, stream>>>(x, W, bias, list, cnt, wout);
        ve_zero_out<<<2048, 256, 0, stream>>>(out, B_N * C_N / 4);
        ve_vote2<<<64, 256, 0, stream>>>(wout, coefs, out);
    } else {
        float2* part = (float2*)d_ws;
        ve_zero_out<<<2048, 256, 0, stream>>>(out, B_N * C_N / 4);
        dim3 grid(CT, B_N / TM, M_N);
        ve_gemm_argmax_fb<<<grid, 256, 0, stream>>>(x, W, bias, part);
        ve_vote_fb<<<(B_N + 255) / 256, 256, 0, stream>>>(part, coefs, out);
    }
}

// Round 4
// 757.714 us; speedup vs baseline: 1.0120x; 1.0120x over previous
//
#include <hip/hip_runtime.h>

#define B_N 16384
#define D_K 512
#define C_N 1000
#define CP 1024
#define M_N 8
#define GAP_EPS 2e-4f
#define NT 48   // virtual K' = 1536 = 48 K-tiles of 32

typedef __attribute__((ext_vector_type(8))) short bf16x8;
typedef __attribute__((ext_vector_type(4))) float f32x4;

typedef const __attribute__((address_space(1))) unsigned int* gptr_t;
typedef __attribute__((address_space(3))) unsigned int* lptr_t;

__device__ __forceinline__ void gload16(const void* g, void* l) {
    __builtin_amdgcn_global_load_lds((gptr_t)g, (lptr_t)l, 16, 0, 0);
}

#define BAR()        asm volatile("s_barrier" ::: "memory")
#define WAIT_LGKM0() asm volatile("s_waitcnt lgkmcnt(0)" ::: "memory")
#define WAIT_VM8()   asm volatile("s_waitcnt vmcnt(8)" ::: "memory")
#define WAIT_VM4()   asm volatile("s_waitcnt vmcnt(4)" ::: "memory")
#define WAIT_VM0()   asm volatile("s_waitcnt vmcnt(0)" ::: "memory")
#define SCHEDB()     __builtin_amdgcn_sched_barrier(0)

__device__ __forceinline__ unsigned short bf16_rn(float f) {
    unsigned u = __float_as_uint(f);
    unsigned lsb = (u >> 16) & 1u;
    u += 0x7FFFu + lsb;
    return (unsigned short)(u >> 16);
}

__device__ __forceinline__ void split2(float f, unsigned short& h, unsigned short& l) {
    unsigned u = __float_as_uint(f) & 0xFFFF0000u;
    h = (unsigned short)(u >> 16);
    float r = f - __uint_as_float(u);
    l = bf16_rn(r);
}

// ---------------- conversion kernels ----------------

__global__ __launch_bounds__(256) void ve_conv_x(const float* __restrict__ x,
        unsigned short* __restrict__ xh, unsigned short* __restrict__ xl,
        unsigned int* __restrict__ cnt) {
    int i = blockIdx.x * 256 + threadIdx.x;
    if (i == 0) *cnt = 0u;
    float4 v = reinterpret_cast<const float4*>(x)[i];
    ushort4 h, l;
    split2(v.x, h.x, l.x); split2(v.y, h.y, l.y);
    split2(v.z, h.z, l.z); split2(v.w, h.w, l.w);
    reinterpret_cast<ushort4*>(xh)[i] = h;
    reinterpret_cast<ushort4*>(xl)[i] = l;
}

__global__ __launch_bounds__(256) void ve_conv_w(const float* __restrict__ W,
        unsigned short* __restrict__ wht, unsigned short* __restrict__ wlt) {
    __shared__ float t[64][65];
    const int m = blockIdx.z, k0 = blockIdx.y * 64, c0 = blockIdx.x * 64;
    const int tid = threadIdx.x;
#pragma unroll
    for (int p = 0; p < 16; ++p) {
        int idx = p * 256 + tid;
        int kk = idx >> 6, cc = idx & 63;
        int c = c0 + cc;
        t[kk][cc] = (c < C_N) ? W[((size_t)m * D_K + k0 + kk) * C_N + c] : 0.f;
    }
    __syncthreads();
#pragma unroll
    for (int p = 0; p < 4; ++p) {
        int idx = p * 256 + tid;
        int cc = idx >> 4, kq = idx & 15;
        ushort4 h, l;
        split2(t[kq * 4 + 0][cc], h.x, l.x);
        split2(t[kq * 4 + 1][cc], h.y, l.y);
        split2(t[kq * 4 + 2][cc], h.z, l.z);
        split2(t[kq * 4 + 3][cc], h.w, l.w);
        size_t o = ((size_t)m * CP + c0 + cc) * D_K + k0 + kq * 4;
        *reinterpret_cast<ushort4*>(wht + o) = h;
        *reinterpret_cast<ushort4*>(wlt + o) = l;
    }
}

// ---------------- pipelined 256x256 MFMA GEMM (virtual K'=1536) ----------------
// Segments: t in [0,16): xh*wh, [16,32): xh*wl, [32,48): xl*wh.
// LDS K-tile buffer = 128 lines x 128B; line L holds rows 2L,2L+1; logical
// slot s3 = (row&1)*4 + kchunk, stored at s3 ^ (L&7)  -> bank-quad = s3'
// covers all 8 quads exactly twice per 16-lane frag read (2-way = free).
// global_load_lds dest stays linear; swizzle pre-applied to global source.

__global__ __launch_bounds__(512, 1) void ve_gemm8(
        const unsigned short* __restrict__ Xh, const unsigned short* __restrict__ Xl,
        const unsigned short* __restrict__ WhT, const unsigned short* __restrict__ WlT,
        const float* __restrict__ bias, float4* __restrict__ part) {
    __shared__ unsigned short Abuf[4][8192];
    __shared__ unsigned short Bbuf[4][8192];
    __shared__ float4 wtop[256][4];
    __shared__ float bs[256];

    const int tid = threadIdx.x;
    const int l = tid & 63, w = tid >> 6;
    const int wr = w >> 2, wc = w & 3;          // 2M x 4N waves; per-wave C = 128x64
    const int l15 = l & 15, kg = l >> 4;
    const int rt = blockIdx.x, ct = blockIdx.y, mb = blockIdx.z;
    const int r0 = rt * 256, c0 = ct * 256;

    // staging lane constants (inverse of the read-side swizzle)
    const int lhi = l >> 3, llo = l & 7;
    const int s3g = llo ^ lhi;
    const int srow16 = (lhi << 1) | (s3g >> 2);   // row within the 16-row wave strip
    const int kgs = (s3g & 3) * 8;                // k-chunk (shorts)

    if (tid < 256) {
        int c = c0 + tid;
        bs[tid] = (c < C_N) ? bias[mb * C_N + c] : -1e30f;
    }

    auto stageQ = [&](int u, int q) {
        if (u >= NT) return;
        const int cu = u & 3;
        const int kb = (u & 15) * 32;
        if (q < 2) {
            const unsigned short* Ap = (u < 32) ? Xh : Xl;
            const unsigned short* g = Ap + (size_t)(r0 + q * 128 + w * 16 + srow16) * D_K + kb + kgs;
            gload16(g, &Abuf[cu][q * 4096 + w * 512]);
        } else {
            const unsigned short* Bp = (u >= 16 && u < 32) ? WlT : WhT;
            const unsigned short* g = Bp + ((size_t)mb * CP + c0 + (q - 2) * 128 + w * 16 + srow16) * D_K + kb + kgs;
            gload16(g, &Bbuf[cu][(q - 2) * 4096 + w * 512]);
        }
    };

    // swizzled LDS read offset (shorts) for (row, kchunk)
    auto ldsoff = [&](int row, int kc) {
        return (row >> 1) * 64 + (((((row & 1) << 2) | kc) ^ ((row >> 1) & 7)) * 8);
    };

    // prologue: stage K-tiles 0,1,2; require tile 0 landed (8 newer in flight).
#pragma unroll
    for (int u = 0; u < 3; ++u) {
        stageQ(u, 0); stageQ(u, 1); stageQ(u, 2); stageQ(u, 3);
    }
    WAIT_VM8();
    BAR();

    f32x4 acc[8][4];
#pragma unroll
    for (int i = 0; i < 8; ++i)
#pragma unroll
        for (int j = 0; j < 4; ++j) acc[i][j] = (f32x4){0.f, 0.f, 0.f, 0.f};

    for (int t = 0; t < NT; ++t) {
        const int c = t & 3;
        const unsigned short* Ab = Abuf[c];
        const unsigned short* Bb = Bbuf[c];
        bf16x8 bf[4], af[4];

        // ---------- phase 0: wave rows 0..63 ----------
#pragma unroll
        for (int j = 0; j < 4; ++j)
            bf[j] = *reinterpret_cast<const bf16x8*>(Bb + ldsoff(wc * 64 + j * 16 + l15, kg));
#pragma unroll
        for (int i = 0; i < 4; ++i)
            af[i] = *reinterpret_cast<const bf16x8*>(Ab + ldsoff(wr * 128 + i * 16 + l15, kg));
        stageQ(t + 3, 0); stageQ(t + 3, 1);
        BAR();
        WAIT_LGKM0(); SCHEDB();
        __builtin_amdgcn_s_setprio(1);
#pragma unroll
        for (int i = 0; i < 4; ++i)
#pragma unroll
            for (int j = 0; j < 4; ++j)
                acc[i][j] = __builtin_amdgcn_mfma_f32_16x16x32_bf16(af[i], bf[j], acc[i][j], 0, 0, 0);
        __builtin_amdgcn_s_setprio(0);
        BAR();

        // ---------- phase 1: wave rows 64..127 ----------
#pragma unroll
        for (int i = 0; i < 4; ++i)
            af[i] = *reinterpret_cast<const bf16x8*>(Ab + ldsoff(wr * 128 + 64 + i * 16 + l15, kg));
        stageQ(t + 3, 2); stageQ(t + 3, 3);
        // counted wait: guarantee tile t+1 landed; keep t+2/t+3 in flight.
        if (t + 3 < NT)      { WAIT_VM8(); }
        else if (t + 2 < NT) { WAIT_VM4(); }
        else                 { WAIT_VM0(); }
        BAR();
        WAIT_LGKM0(); SCHEDB();
        __builtin_amdgcn_s_setprio(1);
#pragma unroll
        for (int i = 0; i < 4; ++i)
#pragma unroll
            for (int j = 0; j < 4; ++j)
                acc[4 + i][j] = __builtin_amdgcn_mfma_f32_16x16x32_bf16(af[i], bf[j], acc[4 + i][j], 0, 0, 0);
        __builtin_amdgcn_s_setprio(0);
        BAR();
    }

    // ---------------- epilogue: bias + per-wave top-2 over its 64 cols ----------------
    float bsv[4]; int cg[4];
#pragma unroll
    for (int j = 0; j < 4; ++j) {
        int cl = wc * 64 + j * 16 + l15;
        bsv[j] = bs[cl];
        cg[j] = c0 + cl;
    }
#pragma unroll
    for (int i = 0; i < 8; ++i) {
#pragma unroll
        for (int reg = 0; reg < 4; ++reg) {
            float v1 = acc[i][0][reg] + bsv[0]; int i1 = cg[0];
            float v2 = -1e30f; int i2 = 0x7fffffff;
#pragma unroll
            for (int j = 1; j < 4; ++j) {
                float v = acc[i][j][reg] + bsv[j]; int cc = cg[j];
                if (v > v1 || (v == v1 && cc < i1)) { v2 = v1; i2 = i1; v1 = v; i1 = cc; }
                else if (v > v2 || (v == v2 && cc < i2)) { v2 = v; i2 = cc; }
            }
#pragma unroll
            for (int mask = 1; mask < 16; mask <<= 1) {
                float ov1 = __shfl_xor(v1, mask); int oi1 = __shfl_xor(i1, mask);
                float ov2 = __shfl_xor(v2, mask); int oi2 = __shfl_xor(i2, mask);
                if (ov1 > v1 || (ov1 == v1 && oi1 < i1)) {
                    float nv2 = v1; int ni2 = i1;
                    if (ov2 > nv2 || (ov2 == nv2 && oi2 < ni2)) { nv2 = ov2; ni2 = oi2; }
                    v1 = ov1; i1 = oi1; v2 = nv2; i2 = ni2;
                } else if (ov1 > v2 || (ov1 == v2 && oi1 < i2)) { v2 = ov1; i2 = oi1; }
            }
            if (l15 == 0) {
                int row = wr * 128 + i * 16 + (l >> 4) * 4 + reg;
                wtop[row][wc] = make_float4(v1, __int_as_float(i1), v2, __int_as_float(i2));
            }
        }
    }
    BAR();
    if (tid < 256) {
        float v1 = -1e30f; int i1 = 0x7fffffff;
        float v2 = -1e30f; int i2 = 0x7fffffff;
#pragma unroll
        for (int s = 0; s < 4; ++s) {
            float4 o = wtop[tid][s];
            float ov1 = o.x; int oi1 = __float_as_int(o.y);
            float ov2 = o.z; int oi2 = __float_as_int(o.w);
            if (ov1 > v1 || (ov1 == v1 && oi1 < i1)) {
                float nv2 = v1; int ni2 = i1;
                if (ov2 > nv2 || (ov2 == nv2 && oi2 < ni2)) { nv2 = ov2; ni2 = oi2; }
                v1 = ov1; i1 = oi1; v2 = nv2; i2 = ni2;
            } else if (ov1 > v2 || (ov1 == v2 && oi1 < i2)) { v2 = ov1; i2 = oi1; }
        }
        part[((size_t)mb * B_N + r0 + tid) * 4 + ct] =
            make_float4(v1, __int_as_float(i1), v2, __int_as_float(i2));
    }
}

// ---------------- merge 4 C-tiles, flag uncertain rows ----------------

__global__ __launch_bounds__(256) void ve_flag4(const float4* __restrict__ part,
        unsigned int* __restrict__ wout, unsigned int* __restrict__ list,
        unsigned int* __restrict__ cnt) {
    int r = blockIdx.x * 256 + threadIdx.x;
#pragma unroll
    for (int m = 0; m < M_N; ++m) {
        float v1 = -1e30f; int i1 = 0x7fffffff;
        float v2 = -1e30f; int i2 = 0x7fffffff;
#pragma unroll
        for (int t = 0; t < 4; ++t) {
            float4 o = part[((size_t)m * B_N + r) * 4 + t];
            float ov1 = o.x; int oi1 = __float_as_int(o.y);
            float ov2 = o.z; int oi2 = __float_as_int(o.w);
            if (ov1 > v1 || (ov1 == v1 && oi1 < i1)) {
                float nv2 = v1; int ni2 = i1;
                if (ov2 > nv2 || (ov2 == nv2 && oi2 < ni2)) { nv2 = ov2; ni2 = oi2; }
                v1 = ov1; i1 = oi1; v2 = nv2; i2 = ni2;
            } else if (ov1 > v2 || (ov1 == v2 && oi1 < i2)) { v2 = ov1; i2 = oi1; }
        }
        wout[m * B_N + r] = (unsigned)i1;
        if (v1 - v2 <= GAP_EPS) {
            unsigned pos = atomicAdd(cnt, 1u);
            list[pos] = (unsigned)(m * B_N + r);
        }
    }
}

// Exact fp32 serial-FMA argmax for flagged rows (numpy-matching accumulation).
__global__ __launch_bounds__(256) void ve_exact(const float* __restrict__ x,
        const float* __restrict__ W, const float* __restrict__ bias,
        const unsigned int* __restrict__ list, const unsigned int* __restrict__ cnt,
        unsigned int* __restrict__ wout) {
    __shared__ float xs[D_K];
    __shared__ float rv[4];
    __shared__ int ri[4];
    const int tid = threadIdx.x;
    const int lane = tid & 63, wv = tid >> 6;
    const unsigned n = *cnt;
    for (unsigned u = blockIdx.x; u < n; u += gridDim.x) {
        unsigned e = list[u];
        int m = (int)(e >> 14), r = (int)(e & (B_N - 1));
        __syncthreads();
        for (int i = tid; i < D_K; i += 256) xs[i] = x[(size_t)r * D_K + i];
        __syncthreads();
        float a0 = 0.f, a1 = 0.f, a2 = 0.f, a3 = 0.f;
        const int g3 = (tid < C_N - 768);
        const int c3 = g3 ? tid + 768 : tid;
        const float* wb = W + (size_t)m * D_K * C_N;
        for (int k = 0; k < D_K; ++k) {
            float xv = xs[k];
            const float* wr_ = wb + (size_t)k * C_N;
            a0 = fmaf(xv, wr_[tid], a0);
            a1 = fmaf(xv, wr_[tid + 256], a1);
            a2 = fmaf(xv, wr_[tid + 512], a2);
            a3 = fmaf(xv, wr_[c3], a3);
        }
        const float* bb = bias + m * C_N;
        float best = a0 + bb[tid]; int bi = tid;
        float v = a1 + bb[tid + 256]; if (v > best) { best = v; bi = tid + 256; }
        v = a2 + bb[tid + 512]; if (v > best) { best = v; bi = tid + 512; }
        if (g3) { v = a3 + bb[tid + 768]; if (v > best) { best = v; bi = tid + 768; } }
#pragma unroll
        for (int mask = 1; mask < 64; mask <<= 1) {
            float ov = __shfl_xor(best, mask); int oi = __shfl_xor(bi, mask);
            if (ov > best || (ov == best && oi < bi)) { best = ov; bi = oi; }
        }
        if (lane == 0) { rv[wv] = best; ri[wv] = bi; }
        __syncthreads();
        if (tid == 0) {
            for (int q = 1; q < 4; ++q)
                if (rv[q] > best || (rv[q] == best && ri[q] < bi)) { best = rv[q]; bi = ri[q]; }
            wout[e] = (unsigned)bi;
        }
    }
}

__global__ __launch_bounds__(256) void ve_zero_out(float* __restrict__ out, int n4) {
    int i = blockIdx.x * blockDim.x + threadIdx.x;
    const float4 z = make_float4(0.f, 0.f, 0.f, 0.f);
    for (; i < n4; i += gridDim.x * blockDim.x)
        reinterpret_cast<float4*>(out)[i] = z;
}

__global__ __launch_bounds__(256) void ve_vote2(const unsigned int* __restrict__ wout,
        const float* __restrict__ coefs, float* __restrict__ out) {
    int r = blockIdx.x * 256 + threadIdx.x;
#pragma unroll
    for (int m = 0; m < M_N; ++m)
        out[(size_t)r * C_N + wout[m * B_N + r]] += coefs[m] * 0.125f;
}

// ================= fallback: proven round-1 fp32 path =================

#define TM 128
#define TN 128
#define TK 32
#define CT 8

__global__ __launch_bounds__(256) void ve_gemm_argmax_fb(
        const float* __restrict__ x, const float* __restrict__ W,
        const float* __restrict__ bias, float2* __restrict__ part) {
    __shared__ float xs[TK][TM + 1];
    __shared__ float ws[TK][TN];
    const int ct = blockIdx.x, rt = blockIdx.y, m = blockIdx.z;
    const int tid = threadIdx.x;
    const int tx = tid & 15, ty = tid >> 4;
    const int r0 = rt * TM, c0 = ct * TN;
    float acc[8][8];
#pragma unroll
    for (int i = 0; i < 8; i++)
#pragma unroll
        for (int j = 0; j < 8; j++) acc[i][j] = 0.f;
    const float* xbase = x + (size_t)r0 * D_K;
    for (int kt = 0; kt < D_K; kt += TK) {
#pragma unroll
        for (int i = 0; i < 4; i++) {
            int l = tid + i * 256;
            int row = l >> 3, kq = l & 7;
            float4 v = *reinterpret_cast<const float4*>(xbase + (size_t)row * D_K + kt + kq * 4);
            int kk = kq * 4;
            xs[kk + 0][row] = v.x; xs[kk + 1][row] = v.y;
            xs[kk + 2][row] = v.z; xs[kk + 3][row] = v.w;
        }
#pragma unroll
        for (int i = 0; i < 4; i++) {
            int l = tid + i * 256;
            int kk = l >> 5, cq = l & 31;
            int c = c0 + cq * 4;
            const float* p = W + ((size_t)(m * D_K + kt + kk)) * C_N + c;
            float4 v;
            if (c + 3 < C_N) v = *reinterpret_cast<const float4*>(p);
            else {
                v.x = (c + 0 < C_N) ? p[0] : 0.f; v.y = (c + 1 < C_N) ? p[1] : 0.f;
                v.z = (c + 2 < C_N) ? p[2] : 0.f; v.w = (c + 3 < C_N) ? p[3] : 0.f;
            }
            ws[kk][cq * 4 + 0] = v.x; ws[kk][cq * 4 + 1] = v.y;
            ws[kk][cq * 4 + 2] = v.z; ws[kk][cq * 4 + 3] = v.w;
        }
        __syncthreads();
        for (int kk = 0; kk < TK; kk++) {
            float a[8], bb[8];
#pragma unroll
            for (int i = 0; i < 8; i++) a[i] = xs[kk][ty + i * 16];
#pragma unroll
            for (int j = 0; j < 8; j++) bb[j] = ws[kk][tx + j * 16];
#pragma unroll
            for (int i = 0; i < 8; i++)
#pragma unroll
                for (int j = 0; j < 8; j++) acc[i][j] += a[i] * bb[j];
        }
        __syncthreads();
    }
    const float NEG_INF = -__builtin_huge_valf();
    float bv[8]; int cv[8];
#pragma unroll
    for (int j = 0; j < 8; j++) {
        int c = c0 + tx + j * 16;
        cv[j] = c;
        bv[j] = (c < C_N) ? bias[m * C_N + c] : 0.f;
    }
#pragma unroll
    for (int i = 0; i < 8; i++) {
        int r = r0 + ty + i * 16;
        float best = NEG_INF; int bidx = 0x7fffffff;
#pragma unroll
        for (int j = 0; j < 8; j++) {
            int c = cv[j];
            float v = (c < C_N) ? (acc[i][j] + bv[j]) : NEG_INF;
            if (v > best || (v == best && c < bidx)) { best = v; bidx = c; }
        }
#pragma unroll
        for (int mask = 1; mask < 16; mask <<= 1) {
            float ov = __shfl_xor(best, mask);
            int oi = __shfl_xor(bidx, mask);
            if (ov > best || (ov == best && oi < bidx)) { best = ov; bidx = oi; }
        }
        if (tx == 0) part[((size_t)m * B_N + r) * CT + ct] = make_float2(best, __int_as_float(bidx));
    }
}

__global__ __launch_bounds__(256) void ve_vote_fb(const float2* __restrict__ part,
        const float* __restrict__ coefs, float* __restrict__ out) {
    int r = blockIdx.x * blockDim.x + threadIdx.x;
    if (r >= B_N) return;
    const float NEG_INF = -__builtin_huge_valf();
#pragma unroll
    for (int m = 0; m < M_N; m++) {
        float best = NEG_INF; int bidx = 0x7fffffff;
#pragma unroll
        for (int ct = 0; ct < CT; ct++) {
            float2 p = part[((size_t)m * B_N + r) * CT + ct];
            int oi = __float_as_int(p.y);
            if (p.x > best || (p.x == best && oi < bidx)) { best = p.x; bidx = oi; }
        }
        out[(size_t)r * C_N + bidx] += coefs[m] * 0.125f;
    }
}

// ================= launcher =================

extern "C" void kernel_launch(void* const* d_in, const int* in_sizes, int n_in,
                              void* d_out, int out_size, void* d_ws, size_t ws_size,
                              hipStream_t stream) {
    const float* x     = (const float*)d_in[0];
    const float* W     = (const float*)d_in[1];
    const float* bias  = (const float*)d_in[2];
    const float* coefs = (const float*)d_in[3];
    float* out = (float*)d_out;

    const size_t NEED = (57ull << 20) + 4096;
    if (ws_size >= NEED) {
        char* ws = (char*)d_ws;
        unsigned short* Xh   = (unsigned short*)(ws);                  // 16 MiB
        unsigned short* Xl   = (unsigned short*)(ws + (16ull << 20));  // 16 MiB
        unsigned short* WhT  = (unsigned short*)(ws + (32ull << 20));  //  8 MiB
        unsigned short* WlT  = (unsigned short*)(ws + (40ull << 20));  //  8 MiB
        float4*         part = (float4*)(ws + (48ull << 20));          //  8 MiB
        unsigned int*   wout = (unsigned int*)(ws + (56ull << 20));    // 512 KiB
        unsigned int*   list = (unsigned int*)(ws + (56ull << 20) + (512ull << 10));
        unsigned int*   cnt  = (unsigned int*)(ws + (57ull << 20));

        ve_conv_x<<<8192, 256, 0, stream>>>(x, Xh, Xl, cnt);
        ve_conv_w<<<dim3(16, 8, 8), 256, 0, stream>>>(W, WhT, WlT);
        ve_gemm8<<<dim3(64, 4, 8), 512, 0, stream>>>(Xh, Xl, WhT, WlT, bias, part);
        ve_flag4<<<64, 256, 0, stream>>>(part, wout, list, cnt);
        ve_exact<<<128, 256, 0, stream>>>(x, W, bias, list, cnt, wout);
        ve_zero_out<<<2048, 256, 0, stream>>>(out, B_N * C_N / 4);
        ve_vote2<<<64, 256, 0, stream>>>(wout, coefs, out);
    } else {
        float2* part = (float2*)d_ws;
        ve_zero_out<<<2048, 256, 0, stream>>>(out, B_N * C_N / 4);
        dim3 grid(CT, B_N / TM, M_N);
        ve_gemm_argmax_fb<<<grid, 256, 0, stream>>>(x, W, bias, part);
        ve_vote_fb<<<(B_N + 255) / 256, 256, 0, stream>>>(part, coefs, out);
    }
}

// Round 5
// 725.486 us; speedup vs baseline: 1.0569x; 1.0444x over previous
//
#include <hip/hip_runtime.h>

#define B_N 16384
#define D_K 512
#define C_N 1000
#define CP 1024
#define M_N 8
#define GAP_EPS 2e-4f
#define NT 48   // virtual K' = 1536 = 48 K-tiles of 32

typedef __attribute__((ext_vector_type(8))) short bf16x8;
typedef __attribute__((ext_vector_type(4))) float f32x4;

typedef const __attribute__((address_space(1))) unsigned int* gptr_t;
typedef __attribute__((address_space(3))) unsigned int* lptr_t;

__device__ __forceinline__ void gload16(const void* g, void* l) {
    __builtin_amdgcn_global_load_lds((gptr_t)g, (lptr_t)l, 16, 0, 0);
}

#define BAR()        asm volatile("s_barrier" ::: "memory")
#define WAIT_LGKM0() asm volatile("s_waitcnt lgkmcnt(0)" ::: "memory")
#define WAIT_VM8()   asm volatile("s_waitcnt vmcnt(8)" ::: "memory")
#define WAIT_VM4()   asm volatile("s_waitcnt vmcnt(4)" ::: "memory")
#define WAIT_VM0()   asm volatile("s_waitcnt vmcnt(0)" ::: "memory")
#define SCHEDB()     __builtin_amdgcn_sched_barrier(0)

__device__ __forceinline__ unsigned short bf16_rn(float f) {
    unsigned u = __float_as_uint(f);
    unsigned lsb = (u >> 16) & 1u;
    u += 0x7FFFu + lsb;
    return (unsigned short)(u >> 16);
}

__device__ __forceinline__ void split2(float f, unsigned short& h, unsigned short& l) {
    unsigned u = __float_as_uint(f) & 0xFFFF0000u;
    h = (unsigned short)(u >> 16);
    float r = f - __uint_as_float(u);
    l = bf16_rn(r);
}

// ---------------- conversion kernels ----------------

__global__ __launch_bounds__(256) void ve_conv_x(const float* __restrict__ x,
        unsigned short* __restrict__ xh, unsigned short* __restrict__ xl,
        unsigned int* __restrict__ cnt) {
    int i = blockIdx.x * 256 + threadIdx.x;
    if (i == 0) *cnt = 0u;
    float4 v = reinterpret_cast<const float4*>(x)[i];
    ushort4 h, l;
    split2(v.x, h.x, l.x); split2(v.y, h.y, l.y);
    split2(v.z, h.z, l.z); split2(v.w, h.w, l.w);
    reinterpret_cast<ushort4*>(xh)[i] = h;
    reinterpret_cast<ushort4*>(xl)[i] = l;
}

__global__ __launch_bounds__(256) void ve_conv_w(const float* __restrict__ W,
        unsigned short* __restrict__ wht, unsigned short* __restrict__ wlt) {
    __shared__ float t[64][65];
    const int m = blockIdx.z, k0 = blockIdx.y * 64, c0 = blockIdx.x * 64;
    const int tid = threadIdx.x;
#pragma unroll
    for (int p = 0; p < 16; ++p) {
        int idx = p * 256 + tid;
        int kk = idx >> 6, cc = idx & 63;
        int c = c0 + cc;
        t[kk][cc] = (c < C_N) ? W[((size_t)m * D_K + k0 + kk) * C_N + c] : 0.f;
    }
    __syncthreads();
#pragma unroll
    for (int p = 0; p < 4; ++p) {
        int idx = p * 256 + tid;
        int cc = idx >> 4, kq = idx & 15;
        ushort4 h, l;
        split2(t[kq * 4 + 0][cc], h.x, l.x);
        split2(t[kq * 4 + 1][cc], h.y, l.y);
        split2(t[kq * 4 + 2][cc], h.z, l.z);
        split2(t[kq * 4 + 3][cc], h.w, l.w);
        size_t o = ((size_t)m * CP + c0 + cc) * D_K + k0 + kq * 4;
        *reinterpret_cast<ushort4*>(wht + o) = h;
        *reinterpret_cast<ushort4*>(wlt + o) = l;
    }
}

// ---------------- pipelined 256x256 MFMA GEMM (virtual K'=1536) ----------------
// Segments: t in [0,16): xh*wh, [16,32): xh*wl, [32,48): xl*wh.
// LDS layout identical to round 4 (verified absmax 0.0). This round: all
// addressing hoisted out of the K-loop — 12 loop-invariant frag vaddrs with
// compile-time buffer immediates, incremental wave-uniform staging pointers.

__global__ __launch_bounds__(512, 1) void ve_gemm8(
        const unsigned short* __restrict__ Xh, const unsigned short* __restrict__ Xl,
        const unsigned short* __restrict__ WhT, const unsigned short* __restrict__ WlT,
        const float* __restrict__ bias, float4* __restrict__ part) {
    __shared__ unsigned short Abuf[4][8192];
    __shared__ unsigned short Bbuf[4][8192];
    __shared__ float4 wtop[256][4];
    __shared__ float bs[256];

    const int tid = threadIdx.x;
    const int l = tid & 63, w = tid >> 6;
    const int wr = w >> 2, wc = w & 3;          // 2M x 4N waves; per-wave C = 128x64
    const int l15 = l & 15, kg = l >> 4;
    const int rt = blockIdx.x, ct = blockIdx.y, mb = blockIdx.z;
    const int r0 = rt * 256, c0 = ct * 256;

    // staging lane constants (inverse of the read-side swizzle)
    const int lhi = l >> 3, llo = l & 7;
    const int s3g = llo ^ lhi;
    const int srow16 = (lhi << 1) | (s3g >> 2);
    const int kgs = (s3g & 3) * 8;
    const int aLane = ((r0 + w * 16 + srow16) * D_K + kgs) * 2;          // bytes
    const int bLane = ((mb * CP + c0 + w * 16 + srow16) * D_K + kgs) * 2;

    if (tid < 256) {
        int c = c0 + tid;
        bs[tid] = (c < C_N) ? bias[mb * C_N + c] : -1e30f;
    }

    // loop-invariant fragment read offsets (bytes within buffer 0)
    auto ldsoff = [&](int row, int kc) {
        return (row >> 1) * 64 + (((((row & 1) << 2) | kc) ^ ((row >> 1) & 7)) * 8);
    };
    const char* abase = (const char*)&Abuf[0][0];
    const char* bbase = (const char*)&Bbuf[0][0];
    unsigned aRd[8], bRd[4];
#pragma unroll
    for (int i = 0; i < 8; ++i) aRd[i] = 2u * ldsoff(wr * 128 + i * 16 + l15, kg);
#pragma unroll
    for (int j = 0; j < 4; ++j) bRd[j] = 2u * ldsoff(wc * 64 + j * 16 + l15, kg);

    // staging state (wave-uniform planes + scalar k-offset; per-lane aLane/bLane)
    const char* pA = (const char*)Xh;
    const char* pB = (const char*)WhT;
    int koff = 0, seg = 0;
    bool stop = false;

#define STAGE_A(SU) do { \
        gload16(pA + koff + aLane,          &Abuf[SU][w * 512]);        \
        gload16(pA + koff + aLane + 131072, &Abuf[SU][4096 + w * 512]); } while (0)
#define STAGE_B(SU) do { \
        gload16(pB + koff + bLane,          &Bbuf[SU][w * 512]);        \
        gload16(pB + koff + bLane + 131072, &Bbuf[SU][4096 + w * 512]); } while (0)

    // prologue: stage K-tiles 0,1,2; require tile 0 landed (8 newer in flight).
    STAGE_A(0); STAGE_B(0); koff = 64;
    STAGE_A(1); STAGE_B(1); koff = 128;
    STAGE_A(2); STAGE_B(2); koff = 192;
    WAIT_VM8();
    BAR();

    f32x4 acc[8][4];
#pragma unroll
    for (int i = 0; i < 8; ++i)
#pragma unroll
        for (int j = 0; j < 4; ++j) acc[i][j] = (f32x4){0.f, 0.f, 0.f, 0.f};

#pragma unroll 1
    for (int qi = 0; qi < 12; ++qi) {
#pragma unroll
        for (int tt = 0; tt < 4; ++tt) {
            const int t = qi * 4 + tt;
            const int cu = tt;              // compute buffer (compile-time)
            const int su = (tt + 3) & 3;    // staging buffer (compile-time)
            bf16x8 bf[4], af[4];

            // ---------- phase 0: wave rows 0..63 ----------
#pragma unroll
            for (int j = 0; j < 4; ++j)
                bf[j] = *reinterpret_cast<const bf16x8*>(bbase + bRd[j] + cu * 16384);
#pragma unroll
            for (int i = 0; i < 4; ++i)
                af[i] = *reinterpret_cast<const bf16x8*>(abase + aRd[i] + cu * 16384);
            if (!stop) STAGE_A(su);
            BAR();
            WAIT_LGKM0(); SCHEDB();
            __builtin_amdgcn_s_setprio(1);
#pragma unroll
            for (int i = 0; i < 4; ++i)
#pragma unroll
                for (int j = 0; j < 4; ++j)
                    acc[i][j] = __builtin_amdgcn_mfma_f32_16x16x32_bf16(af[i], bf[j], acc[i][j], 0, 0, 0);
            __builtin_amdgcn_s_setprio(0);
            BAR();

            // ---------- phase 1: wave rows 64..127 ----------
#pragma unroll
            for (int i = 0; i < 4; ++i)
                af[i] = *reinterpret_cast<const bf16x8*>(abase + aRd[4 + i] + cu * 16384);
            if (!stop) {
                STAGE_B(su);
                koff += 64;
                if (koff == 1024) {          // staging crossed a 16-tile segment
                    koff = 0; ++seg;
                    if (seg == 1)      { pB = (const char*)WlT; }
                    else if (seg == 2) { pA = (const char*)Xl; pB = (const char*)WhT; }
                    else               { stop = true; }
                }
            }
            if (t + 3 < NT)      { WAIT_VM8(); }
            else if (t + 2 < NT) { WAIT_VM4(); }
            else                 { WAIT_VM0(); }
            BAR();
            WAIT_LGKM0(); SCHEDB();
            __builtin_amdgcn_s_setprio(1);
#pragma unroll
            for (int i = 0; i < 4; ++i)
#pragma unroll
                for (int j = 0; j < 4; ++j)
                    acc[4 + i][j] = __builtin_amdgcn_mfma_f32_16x16x32_bf16(af[i], bf[j], acc[4 + i][j], 0, 0, 0);
            __builtin_amdgcn_s_setprio(0);
            BAR();
        }
    }
#undef STAGE_A
#undef STAGE_B

    // ---------------- epilogue: bias + per-wave top-2 over its 64 cols ----------------
    float bsv[4]; int cg[4];
#pragma unroll
    for (int j = 0; j < 4; ++j) {
        int cl = wc * 64 + j * 16 + l15;
        bsv[j] = bs[cl];
        cg[j] = c0 + cl;
    }
#pragma unroll
    for (int i = 0; i < 8; ++i) {
#pragma unroll
        for (int reg = 0; reg < 4; ++reg) {
            float v1 = acc[i][0][reg] + bsv[0]; int i1 = cg[0];
            float v2 = -1e30f; int i2 = 0x7fffffff;
#pragma unroll
            for (int j = 1; j < 4; ++j) {
                float v = acc[i][j][reg] + bsv[j]; int cc = cg[j];
                if (v > v1 || (v == v1 && cc < i1)) { v2 = v1; i2 = i1; v1 = v; i1 = cc; }
                else if (v > v2 || (v == v2 && cc < i2)) { v2 = v; i2 = cc; }
            }
#pragma unroll
            for (int mask = 1; mask < 16; mask <<= 1) {
                float ov1 = __shfl_xor(v1, mask); int oi1 = __shfl_xor(i1, mask);
                float ov2 = __shfl_xor(v2, mask); int oi2 = __shfl_xor(i2, mask);
                if (ov1 > v1 || (ov1 == v1 && oi1 < i1)) {
                    float nv2 = v1; int ni2 = i1;
                    if (ov2 > nv2 || (ov2 == nv2 && oi2 < ni2)) { nv2 = ov2; ni2 = oi2; }
                    v1 = ov1; i1 = oi1; v2 = nv2; i2 = ni2;
                } else if (ov1 > v2 || (ov1 == v2 && oi1 < i2)) { v2 = ov1; i2 = oi1; }
            }
            if (l15 == 0) {
                int row = wr * 128 + i * 16 + (l >> 4) * 4 + reg;
                wtop[row][wc] = make_float4(v1, __int_as_float(i1), v2, __int_as_float(i2));
            }
        }
    }
    BAR();
    if (tid < 256) {
        float v1 = -1e30f; int i1 = 0x7fffffff;
        float v2 = -1e30f; int i2 = 0x7fffffff;
#pragma unroll
        for (int s = 0; s < 4; ++s) {
            float4 o = wtop[tid][s];
            float ov1 = o.x; int oi1 = __float_as_int(o.y);
            float ov2 = o.z; int oi2 = __float_as_int(o.w);
            if (ov1 > v1 || (ov1 == v1 && oi1 < i1)) {
                float nv2 = v1; int ni2 = i1;
                if (ov2 > nv2 || (ov2 == nv2 && oi2 < ni2)) { nv2 = ov2; ni2 = oi2; }
                v1 = ov1; i1 = oi1; v2 = nv2; i2 = ni2;
            } else if (ov1 > v2 || (ov1 == v2 && oi1 < i2)) { v2 = ov1; i2 = oi1; }
        }
        part[((size_t)mb * B_N + r0 + tid) * 4 + ct] =
            make_float4(v1, __int_as_float(i1), v2, __int_as_float(i2));
    }
}

// ---------------- merge 4 C-tiles, flag uncertain rows ----------------

__global__ __launch_bounds__(256) void ve_flag4(const float4* __restrict__ part,
        unsigned int* __restrict__ wout, unsigned int* __restrict__ list,
        unsigned int* __restrict__ cnt) {
    int r = blockIdx.x * 256 + threadIdx.x;
#pragma unroll
    for (int m = 0; m < M_N; ++m) {
        float v1 = -1e30f; int i1 = 0x7fffffff;
        float v2 = -1e30f; int i2 = 0x7fffffff;
#pragma unroll
        for (int t = 0; t < 4; ++t) {
            float4 o = part[((size_t)m * B_N + r) * 4 + t];
            float ov1 = o.x; int oi1 = __float_as_int(o.y);
            float ov2 = o.z; int oi2 = __float_as_int(o.w);
            if (ov1 > v1 || (ov1 == v1 && oi1 < i1)) {
                float nv2 = v1; int ni2 = i1;
                if (ov2 > nv2 || (ov2 == nv2 && oi2 < ni2)) { nv2 = ov2; ni2 = oi2; }
                v1 = ov1; i1 = oi1; v2 = nv2; i2 = ni2;
            } else if (ov1 > v2 || (ov1 == v2 && oi1 < i2)) { v2 = ov1; i2 = oi1; }
        }
        wout[m * B_N + r] = (unsigned)i1;
        if (v1 - v2 <= GAP_EPS) {
            unsigned pos = atomicAdd(cnt, 1u);
            list[pos] = (unsigned)(m * B_N + r);
        }
    }
}

// Exact fp32 serial-FMA argmax for flagged rows (numpy-matching accumulation).
__global__ __launch_bounds__(256) void ve_exact(const float* __restrict__ x,
        const float* __restrict__ W, const float* __restrict__ bias,
        const unsigned int* __restrict__ list, const unsigned int* __restrict__ cnt,
        unsigned int* __restrict__ wout) {
    __shared__ float xs[D_K];
    __shared__ float rv[4];
    __shared__ int ri[4];
    const int tid = threadIdx.x;
    const int lane = tid & 63, wv = tid >> 6;
    const unsigned n = *cnt;
    for (unsigned u = blockIdx.x; u < n; u += gridDim.x) {
        unsigned e = list[u];
        int m = (int)(e >> 14), r = (int)(e & (B_N - 1));
        __syncthreads();
        for (int i = tid; i < D_K; i += 256) xs[i] = x[(size_t)r * D_K + i];
        __syncthreads();
        float a0 = 0.f, a1 = 0.f, a2 = 0.f, a3 = 0.f;
        const int g3 = (tid < C_N - 768);
        const int c3 = g3 ? tid + 768 : tid;
        const float* wb = W + (size_t)m * D_K * C_N;
        for (int k = 0; k < D_K; ++k) {
            float xv = xs[k];
            const float* wr_ = wb + (size_t)k * C_N;
            a0 = fmaf(xv, wr_[tid], a0);
            a1 = fmaf(xv, wr_[tid + 256], a1);
            a2 = fmaf(xv, wr_[tid + 512], a2);
            a3 = fmaf(xv, wr_[c3], a3);
        }
        const float* bb = bias + m * C_N;
        float best = a0 + bb[tid]; int bi = tid;
        float v = a1 + bb[tid + 256]; if (v > best) { best = v; bi = tid + 256; }
        v = a2 + bb[tid + 512]; if (v > best) { best = v; bi = tid + 512; }
        if (g3) { v = a3 + bb[tid + 768]; if (v > best) { best = v; bi = tid + 768; } }
#pragma unroll
        for (int mask = 1; mask < 64; mask <<= 1) {
            float ov = __shfl_xor(best, mask); int oi = __shfl_xor(bi, mask);
            if (ov > best || (ov == best && oi < bi)) { best = ov; bi = oi; }
        }
        if (lane == 0) { rv[wv] = best; ri[wv] = bi; }
        __syncthreads();
        if (tid == 0) {
            for (int q = 1; q < 4; ++q)
                if (rv[q] > best || (rv[q] == best && ri[q] < bi)) { best = rv[q]; bi = ri[q]; }
            wout[e] = (unsigned)bi;
        }
    }
}

__global__ __launch_bounds__(256) void ve_zero_out(float* __restrict__ out, int n4) {
    int i = blockIdx.x * blockDim.x + threadIdx.x;
    const float4 z = make_float4(0.f, 0.f, 0.f, 0.f);
    for (; i < n4; i += gridDim.x * blockDim.x)
        reinterpret_cast<float4*>(out)[i] = z;
}

__global__ __launch_bounds__(256) void ve_vote2(const unsigned int* __restrict__ wout,
        const float* __restrict__ coefs, float* __restrict__ out) {
    int r = blockIdx.x * 256 + threadIdx.x;
#pragma unroll
    for (int m = 0; m < M_N; ++m)
        out[(size_t)r * C_N + wout[m * B_N + r]] += coefs[m] * 0.125f;
}

// ================= fallback: proven round-1 fp32 path =================

#define TM 128
#define TN 128
#define TK 32
#define CT 8

__global__ __launch_bounds__(256) void ve_gemm_argmax_fb(
        const float* __restrict__ x, const float* __restrict__ W,
        const float* __restrict__ bias, float2* __restrict__ part) {
    __shared__ float xs[TK][TM + 1];
    __shared__ float ws[TK][TN];
    const int ct = blockIdx.x, rt = blockIdx.y, m = blockIdx.z;
    const int tid = threadIdx.x;
    const int tx = tid & 15, ty = tid >> 4;
    const int r0 = rt * TM, c0 = ct * TN;
    float acc[8][8];
#pragma unroll
    for (int i = 0; i < 8; i++)
#pragma unroll
        for (int j = 0; j < 8; j++) acc[i][j] = 0.f;
    const float* xbase = x + (size_t)r0 * D_K;
    for (int kt = 0; kt < D_K; kt += TK) {
#pragma unroll
        for (int i = 0; i < 4; i++) {
            int l = tid + i * 256;
            int row = l >> 3, kq = l & 7;
            float4 v = *reinterpret_cast<const float4*>(xbase + (size_t)row * D_K + kt + kq * 4);
            int kk = kq * 4;
            xs[kk + 0][row] = v.x; xs[kk + 1][row] = v.y;
            xs[kk + 2][row] = v.z; xs[kk + 3][row] = v.w;
        }
#pragma unroll
        for (int i = 0; i < 4; i++) {
            int l = tid + i * 256;
            int kk = l >> 5, cq = l & 31;
            int c = c0 + cq * 4;
            const float* p = W + ((size_t)(m * D_K + kt + kk)) * C_N + c;
            float4 v;
            if (c + 3 < C_N) v = *reinterpret_cast<const float4*>(p);
            else {
                v.x = (c + 0 < C_N) ? p[0] : 0.f; v.y = (c + 1 < C_N) ? p[1] : 0.f;
                v.z = (c + 2 < C_N) ? p[2] : 0.f; v.w = (c + 3 < C_N) ? p[3] : 0.f;
            }
            ws[kk][cq * 4 + 0] = v.x; ws[kk][cq * 4 + 1] = v.y;
            ws[kk][cq * 4 + 2] = v.z; ws[kk][cq * 4 + 3] = v.w;
        }
        __syncthreads();
        for (int kk = 0; kk < TK; kk++) {
            float a[8], bb[8];
#pragma unroll
            for (int i = 0; i < 8; i++) a[i] = xs[kk][ty + i * 16];
#pragma unroll
            for (int j = 0; j < 8; j++) bb[j] = ws[kk][tx + j * 16];
#pragma unroll
            for (int i = 0; i < 8; i++)
#pragma unroll
                for (int j = 0; j < 8; j++) acc[i][j] += a[i] * bb[j];
        }
        __syncthreads();
    }
    const float NEG_INF = -__builtin_huge_valf();
    float bv[8]; int cv[8];
#pragma unroll
    for (int j = 0; j < 8; j++) {
        int c = c0 + tx + j * 16;
        cv[j] = c;
        bv[j] = (c < C_N) ? bias[m * C_N + c] : 0.f;
    }
#pragma unroll
    for (int i = 0; i < 8; i++) {
        int r = r0 + ty + i * 16;
        float best = NEG_INF; int bidx = 0x7fffffff;
#pragma unroll
        for (int j = 0; j < 8; j++) {
            int c = cv[j];
            float v = (c < C_N) ? (acc[i][j] + bv[j]) : NEG_INF;
            if (v > best || (v == best && c < bidx)) { best = v; bidx = c; }
        }
#pragma unroll
        for (int mask = 1; mask < 16; mask <<= 1) {
            float ov = __shfl_xor(best, mask);
            int oi = __shfl_xor(bidx, mask);
            if (ov > best || (ov == best && oi < bidx)) { best = ov; bidx = oi; }
        }
        if (tx == 0) part[((size_t)m * B_N + r) * CT + ct] = make_float2(best, __int_as_float(bidx));
    }
}

__global__ __launch_bounds__(256) void ve_vote_fb(const float2* __restrict__ part,
        const float* __restrict__ coefs, float* __restrict__ out) {
    int r = blockIdx.x * blockDim.x + threadIdx.x;
    if (r >= B_N) return;
    const float NEG_INF = -__builtin_huge_valf();
#pragma unroll
    for (int m = 0; m < M_N; m++) {
        float best = NEG_INF; int bidx = 0x7fffffff;
#pragma unroll
        for (int ct = 0; ct < CT; ct++) {
            float2 p = part[((size_t)m * B_N + r) * CT + ct];
            int oi = __float_as_int(p.y);
            if (p.x > best || (p.x == best && oi < bidx)) { best = p.x; bidx = oi; }
        }
        out[(size_t)r * C_N + bidx] += coefs[m] * 0.125f;
    }
}

// ================= launcher =================

extern "C" void kernel_launch(void* const* d_in, const int* in_sizes, int n_in,
                              void* d_out, int out_size, void* d_ws, size_t ws_size,
                              hipStream_t stream) {
    const float* x     = (const float*)d_in[0];
    const float* W     = (const float*)d_in[1];
    const float* bias  = (const float*)d_in[2];
    const float* coefs = (const float*)d_in[3];
    float* out = (float*)d_out;

    const size_t NEED = (57ull << 20) + 4096;
    if (ws_size >= NEED) {
        char* ws = (char*)d_ws;
        unsigned short* Xh   = (unsigned short*)(ws);                  // 16 MiB
        unsigned short* Xl   = (unsigned short*)(ws + (16ull << 20));  // 16 MiB
        unsigned short* WhT  = (unsigned short*)(ws + (32ull << 20));  //  8 MiB
        unsigned short* WlT  = (unsigned short*)(ws + (40ull << 20));  //  8 MiB
        float4*         part = (float4*)(ws + (48ull << 20));          //  8 MiB
        unsigned int*   wout = (unsigned int*)(ws + (56ull << 20));    // 512 KiB
        unsigned int*   list = (unsigned int*)(ws + (56ull << 20) + (512ull << 10));
        unsigned int*   cnt  = (unsigned int*)(ws + (57ull << 20));

        ve_conv_x<<<8192, 256, 0, stream>>>(x, Xh, Xl, cnt);
        ve_conv_w<<<dim3(16, 8, 8), 256, 0, stream>>>(W, WhT, WlT);
        ve_gemm8<<<dim3(64, 4, 8), 512, 0, stream>>>(Xh, Xl, WhT, WlT, bias, part);
        ve_flag4<<<64, 256, 0, stream>>>(part, wout, list, cnt);
        ve_exact<<<128, 256, 0, stream>>>(x, W, bias, list, cnt, wout);
        ve_zero_out<<<2048, 256, 0, stream>>>(out, B_N * C_N / 4);
        ve_vote2<<<64, 256, 0, stream>>>(wout, coefs, out);
    } else {
        float2* part = (float2*)d_ws;
        ve_zero_out<<<2048, 256, 0, stream>>>(out, B_N * C_N / 4);
        dim3 grid(CT, B_N / TM, M_N);
        ve_gemm_argmax_fb<<<grid, 256, 0, stream>>>(x, W, bias, part);
        ve_vote_fb<<<(B_N + 255) / 256, 256, 0, stream>>>(part, coefs, out);
    }
}

// Round 7
// 709.878 us; speedup vs baseline: 1.0801x; 1.0220x over previous
//
#include <hip/hip_runtime.h>

#define B_N 16384
#define D_K 512
#define C_N 1000
#define CP 1024
#define M_N 8
#define GAP_EPS 2e-4f

typedef __attribute__((ext_vector_type(8))) short bf16x8;
typedef __attribute__((ext_vector_type(4))) float f32x4;

typedef const __attribute__((address_space(1))) unsigned int* gptr_t;
typedef __attribute__((address_space(3))) unsigned int* lptr_t;

__device__ __forceinline__ void gload16(const void* g, void* l) {
    __builtin_amdgcn_global_load_lds((gptr_t)g, (lptr_t)l, 16, 0, 0);
}

#define BAR()        asm volatile("s_barrier" ::: "memory")
#define WAIT_LGKM0() asm volatile("s_waitcnt lgkmcnt(0)" ::: "memory")
#define WAIT_VM4()   asm volatile("s_waitcnt vmcnt(4)" ::: "memory")
#define WAIT_VM0()   asm volatile("s_waitcnt vmcnt(0)" ::: "memory")
#define SCHEDB()     __builtin_amdgcn_sched_barrier(0)

__device__ __forceinline__ unsigned short bf16_rn(float f) {
    unsigned u = __float_as_uint(f);
    unsigned lsb = (u >> 16) & 1u;
    u += 0x7FFFu + lsb;
    return (unsigned short)(u >> 16);
}

__device__ __forceinline__ void split2(float f, unsigned short& h, unsigned short& l) {
    unsigned u = __float_as_uint(f) & 0xFFFF0000u;
    h = (unsigned short)(u >> 16);
    float r = f - __uint_as_float(u);
    l = bf16_rn(r);
}

// ---------------- conversion kernels ----------------

__global__ __launch_bounds__(256) void ve_conv_x(const float* __restrict__ x,
        unsigned short* __restrict__ xh, unsigned short* __restrict__ xl,
        unsigned int* __restrict__ cnt) {
    int i = blockIdx.x * 256 + threadIdx.x;
    if (i == 0) *cnt = 0u;
    float4 v = reinterpret_cast<const float4*>(x)[i];
    ushort4 h, l;
    split2(v.x, h.x, l.x); split2(v.y, h.y, l.y);
    split2(v.z, h.z, l.z); split2(v.w, h.w, l.w);
    reinterpret_cast<ushort4*>(xh)[i] = h;
    reinterpret_cast<ushort4*>(xl)[i] = l;
}

__global__ __launch_bounds__(256) void ve_conv_w(const float* __restrict__ W,
        unsigned short* __restrict__ wht, unsigned short* __restrict__ wlt) {
    __shared__ float t[64][65];
    const int m = blockIdx.z, k0 = blockIdx.y * 64, c0 = blockIdx.x * 64;
    const int tid = threadIdx.x;
#pragma unroll
    for (int p = 0; p < 16; ++p) {
        int idx = p * 256 + tid;
        int kk = idx >> 6, cc = idx & 63;
        int c = c0 + cc;
        t[kk][cc] = (c < C_N) ? W[((size_t)m * D_K + k0 + kk) * C_N + c] : 0.f;
    }
    __syncthreads();
#pragma unroll
    for (int p = 0; p < 4; ++p) {
        int idx = p * 256 + tid;
        int cc = idx >> 4, kq = idx & 15;
        ushort4 h, l;
        split2(t[kq * 4 + 0][cc], h.x, l.x);
        split2(t[kq * 4 + 1][cc], h.y, l.y);
        split2(t[kq * 4 + 2][cc], h.z, l.z);
        split2(t[kq * 4 + 3][cc], h.w, l.w);
        size_t o = ((size_t)m * CP + c0 + cc) * D_K + k0 + kq * 4;
        *reinterpret_cast<ushort4*>(wht + o) = h;
        *reinterpret_cast<ushort4*>(wlt + o) = l;
    }
}

// ------------- 8-phase 256x256 GEMM, BK=64, 24 K-tiles (corrected staging) -------------
// Tiles T=0..23: seg = T>>3 (0: xh*wh, 1: xh*wl, 2: xl*wh), k = (T&7)*64.
// LDS: Ab/Bb = [dbuf=T&1][128B rows x 256]; slot swizzle slot^= (row&7),
// inverse pre-applied on global source (kswz=(l&7)^(l>>3)); gload dest linear.
//
// Liveness per tile in its dbuf: B last read ph2 (held in regs after),
// A last read ph4. Staging (WAR-safe, each after last-read's barrier):
//   ph1: A(2i+1,h0)  ph2: A(2i+1,h1)   [dbuf1-A free since prev ph8]
//   ph3: B(2i+2,h0)  ph4: B(2i+2,h1) + vmcnt(4)  [dbuf0-B free after ph2]
//   ph5: A(2i+2,h0)  ph6: A(2i+2,h1)   [dbuf0-A free after ph4]
//   ph7: B(2i+3,h0)  ph8: B(2i+3,h1) + vmcnt(4)  [dbuf1-B free after ph6]
// vmcnt(4)@ph4 retires B(2i+1)+A(2i+1) (tile 2i+1 ready for ph5);
// vmcnt(4)@ph8 retires B(2i+2)+A(2i+2) (tile 2i+2 ready for next ph1).

#define LD_A4(D, A, P) do { \
    af[0] = *reinterpret_cast<const bf16x8*>((P) + (D)*32768 + ((A)*64 +  0)*128); \
    af[1] = *reinterpret_cast<const bf16x8*>((P) + (D)*32768 + ((A)*64 + 16)*128); \
    af[2] = *reinterpret_cast<const bf16x8*>((P) + (D)*32768 + ((A)*64 + 32)*128); \
    af[3] = *reinterpret_cast<const bf16x8*>((P) + (D)*32768 + ((A)*64 + 48)*128); } while (0)

#define LD_B4(DST, D, P) do { \
    DST[0] = *reinterpret_cast<const bf16x8*>((P) + (D)*32768 +    0); \
    DST[1] = *reinterpret_cast<const bf16x8*>((P) + (D)*32768 + 2048); \
    DST[2] = *reinterpret_cast<const bf16x8*>((P) + (D)*32768 + 4096); \
    DST[3] = *reinterpret_cast<const bf16x8*>((P) + (D)*32768 + 6144); } while (0)

#define PH(AB, BR) do { \
    BAR(); WAIT_LGKM0(); SCHEDB(); \
    __builtin_amdgcn_s_setprio(1); \
    _Pragma("unroll") \
    for (int ii = 0; ii < 4; ++ii) { \
        _Pragma("unroll") \
        for (int jj = 0; jj < 4; ++jj) \
            acc[(AB) + ii][jj] = __builtin_amdgcn_mfma_f32_16x16x32_bf16(af[ii], BR[jj], acc[(AB) + ii][jj], 0, 0, 0); \
    } \
    __builtin_amdgcn_s_setprio(0); \
    BAR(); } while (0)

__global__ __launch_bounds__(512, 2) void ve_gemm8(
        const unsigned short* __restrict__ Xh, const unsigned short* __restrict__ Xl,
        const unsigned short* __restrict__ WhT, const unsigned short* __restrict__ WlT,
        const float* __restrict__ bias, float4* __restrict__ part) {
    __shared__ unsigned short Ab[32768];   // 64 KB
    __shared__ unsigned short Bb[32768];   // 64 KB
    __shared__ float4 wtop[256][4];
    __shared__ float bs[256];

    const int tid = threadIdx.x;
    const int l = tid & 63, w = tid >> 6;
    const int wr = w >> 2, wc = w & 3;          // 2M x 4N waves; per-wave C = 128x64
    const int l15 = l & 15, kg = l >> 4;
    const int rt = blockIdx.x, ct = blockIdx.y, mb = blockIdx.z;
    const int r0 = rt * 256, c0 = ct * 256;

    if (tid < 256) {
        int c = c0 + tid;
        bs[tid] = (c < C_N) ? bias[mb * C_N + c] : -1e30f;
    }

    // ---- staging lane constants ----
    const int kswz = (l & 7) ^ (l >> 3);
    const size_t laneOff = (size_t)((w * 8 + (l >> 3)) * 1024 + kswz * 16);
    const char* xhB = (const char*)Xh + (size_t)r0 * 1024 + laneOff;
    const char* xlB = (const char*)Xl + (size_t)r0 * 1024 + laneOff;
    const char* whB = (const char*)WhT + (size_t)(mb * CP + c0) * 1024 + laneOff;
    const char* wlB = (const char*)WlT + (size_t)(mb * CP + c0) * 1024 + laneOff;

    auto stageA = [&](int T, int half) {
        const char* g = ((T < 16) ? xhB : xlB) + ((T & 7) * 128 + half * 131072);
        unsigned short* d0 = Ab + ((T & 1) * 16384 + half * 8192 + tid * 8);
        gload16(g, d0);
        gload16(g + 65536, d0 + 4096);
    };
    auto stageB = [&](int T, int half) {
        const char* g = (((T >> 3) == 1) ? wlB : whB) + ((T & 7) * 128 + half * 131072);
        unsigned short* d0 = Bb + ((T & 1) * 16384 + half * 8192 + tid * 8);
        gload16(g, d0);
        gload16(g + 65536, d0 + 4096);
    };

    // ---- fragment read base pointers (per-lane, loop-invariant) ----
    const char* aB = (const char*)Ab + wr * 16384 + l15 * 128;
    const char* vA0 = aB + ((kg       ^ (l15 & 7)) * 16);
    const char* vA1 = aB + (((4 | kg) ^ (l15 & 7)) * 16);
    const char* bB = (const char*)Bb + wc * 8192 + l15 * 128;
    const char* vB0 = bB + ((kg       ^ (l15 & 7)) * 16);
    const char* vB1 = bB + (((4 | kg) ^ (l15 & 7)) * 16);

    // ---- prologue: stage tiles 0,1 fully ----
    stageA(0, 0); stageB(0, 1); stageA(0, 1); stageB(0, 0);
    stageA(1, 0); stageB(1, 1); stageA(1, 1); stageB(1, 0);
    __syncthreads();   // vmcnt(0) + lgkm(0) + barrier

    f32x4 acc[8][4];
#pragma unroll
    for (int i = 0; i < 8; ++i)
#pragma unroll
        for (int j = 0; j < 4; ++j) acc[i][j] = (f32x4){0.f, 0.f, 0.f, 0.f};

    bf16x8 af[4], b0r[4], b1r[4];

#pragma unroll 1
    for (int i = 0; i < 12; ++i) {
        // ===== tile 2i (dbuf 0), phases 1..4 =====
        LD_B4(b0r, 0, vB0);
        LD_A4(0, 0, vA0);
        if (i > 0) stageA(2 * i + 1, 0);
        PH(0, b0r);

        LD_B4(b1r, 0, vB1);
        LD_A4(0, 0, vA1);
        if (i > 0) stageA(2 * i + 1, 1);
        PH(0, b1r);

        LD_A4(0, 1, vA1);
        if (i < 11) stageB(2 * i + 2, 0);
        PH(4, b1r);

        LD_A4(0, 1, vA0);
        if (i < 11) { stageB(2 * i + 2, 1); WAIT_VM4(); }
        else        { WAIT_VM0(); }
        PH(4, b0r);

        // ===== tile 2i+1 (dbuf 1), phases 5..8 =====
        LD_B4(b0r, 1, vB0);
        LD_A4(1, 0, vA0);
        if (i < 11) stageA(2 * i + 2, 0);
        PH(0, b0r);

        LD_B4(b1r, 1, vB1);
        LD_A4(1, 0, vA1);
        if (i < 11) stageA(2 * i + 2, 1);
        PH(0, b1r);

        LD_A4(1, 1, vA1);
        if (i < 11) stageB(2 * i + 3, 0);
        PH(4, b1r);

        LD_A4(1, 1, vA0);
        if (i < 11) { stageB(2 * i + 3, 1); WAIT_VM4(); }
        else        { WAIT_VM0(); }
        PH(4, b0r);
    }

    // ---------------- epilogue: bias + per-wave top-2 over its 64 cols ----------------
    float bsv[4]; int cg[4];
#pragma unroll
    for (int j = 0; j < 4; ++j) {
        int cl = wc * 64 + j * 16 + l15;
        bsv[j] = bs[cl];
        cg[j] = c0 + cl;
    }
#pragma unroll
    for (int i = 0; i < 8; ++i) {
#pragma unroll
        for (int reg = 0; reg < 4; ++reg) {
            float v1 = acc[i][0][reg] + bsv[0]; int i1 = cg[0];
            float v2 = -1e30f; int i2 = 0x7fffffff;
#pragma unroll
            for (int j = 1; j < 4; ++j) {
                float v = acc[i][j][reg] + bsv[j]; int cc = cg[j];
                if (v > v1 || (v == v1 && cc < i1)) { v2 = v1; i2 = i1; v1 = v; i1 = cc; }
                else if (v > v2 || (v == v2 && cc < i2)) { v2 = v; i2 = cc; }
            }
#pragma unroll
            for (int mask = 1; mask < 16; mask <<= 1) {
                float ov1 = __shfl_xor(v1, mask); int oi1 = __shfl_xor(i1, mask);
                float ov2 = __shfl_xor(v2, mask); int oi2 = __shfl_xor(i2, mask);
                if (ov1 > v1 || (ov1 == v1 && oi1 < i1)) {
                    float nv2 = v1; int ni2 = i1;
                    if (ov2 > nv2 || (ov2 == nv2 && oi2 < ni2)) { nv2 = ov2; ni2 = oi2; }
                    v1 = ov1; i1 = oi1; v2 = nv2; i2 = ni2;
                } else if (ov1 > v2 || (ov1 == v2 && oi1 < i2)) { v2 = ov1; i2 = oi1; }
            }
            if (l15 == 0) {
                int row = wr * 128 + i * 16 + (l >> 4) * 4 + reg;
                wtop[row][wc] = make_float4(v1, __int_as_float(i1), v2, __int_as_float(i2));
            }
        }
    }
    __syncthreads();
    if (tid < 256) {
        float v1 = -1e30f; int i1 = 0x7fffffff;
        float v2 = -1e30f; int i2 = 0x7fffffff;
#pragma unroll
        for (int s = 0; s < 4; ++s) {
            float4 o = wtop[tid][s];
            float ov1 = o.x; int oi1 = __float_as_int(o.y);
            float ov2 = o.z; int oi2 = __float_as_int(o.w);
            if (ov1 > v1 || (ov1 == v1 && oi1 < i1)) {
                float nv2 = v1; int ni2 = i1;
                if (ov2 > nv2 || (ov2 == nv2 && oi2 < ni2)) { nv2 = ov2; ni2 = oi2; }
                v1 = ov1; i1 = oi1; v2 = nv2; i2 = ni2;
            } else if (ov1 > v2 || (ov1 == v2 && oi1 < i2)) { v2 = ov1; i2 = oi1; }
        }
        part[((size_t)mb * B_N + r0 + tid) * 4 + ct] =
            make_float4(v1, __int_as_float(i1), v2, __int_as_float(i2));
    }
}

// ---------------- merge 4 C-tiles, flag uncertain rows ----------------

__global__ __launch_bounds__(256) void ve_flag4(const float4* __restrict__ part,
        unsigned int* __restrict__ wout, unsigned int* __restrict__ list,
        unsigned int* __restrict__ cnt) {
    int r = blockIdx.x * 256 + threadIdx.x;
#pragma unroll
    for (int m = 0; m < M_N; ++m) {
        float v1 = -1e30f; int i1 = 0x7fffffff;
        float v2 = -1e30f; int i2 = 0x7fffffff;
#pragma unroll
        for (int t = 0; t < 4; ++t) {
            float4 o = part[((size_t)m * B_N + r) * 4 + t];
            float ov1 = o.x; int oi1 = __float_as_int(o.y);
            float ov2 = o.z; int oi2 = __float_as_int(o.w);
            if (ov1 > v1 || (ov1 == v1 && oi1 < i1)) {
                float nv2 = v1; int ni2 = i1;
                if (ov2 > nv2 || (ov2 == nv2 && oi2 < ni2)) { nv2 = ov2; ni2 = oi2; }
                v1 = ov1; i1 = oi1; v2 = nv2; i2 = ni2;
            } else if (ov1 > v2 || (ov1 == v2 && oi1 < i2)) { v2 = ov1; i2 = oi1; }
        }
        wout[m * B_N + r] = (unsigned)i1;
        if (v1 - v2 <= GAP_EPS) {
            unsigned pos = atomicAdd(cnt, 1u);
            list[pos] = (unsigned)(m * B_N + r);
        }
    }
}

// Exact fp32 serial-FMA argmax for flagged rows (numpy-matching accumulation).
__global__ __launch_bounds__(256) void ve_exact(const float* __restrict__ x,
        const float* __restrict__ W, const float* __restrict__ bias,
        const unsigned int* __restrict__ list, const unsigned int* __restrict__ cnt,
        unsigned int* __restrict__ wout) {
    __shared__ float xs[D_K];
    __shared__ float rv[4];
    __shared__ int ri[4];
    const int tid = threadIdx.x;
    const int lane = tid & 63, wv = tid >> 6;
    const unsigned n = *cnt;
    for (unsigned u = blockIdx.x; u < n; u += gridDim.x) {
        unsigned e = list[u];
        int m = (int)(e >> 14), r = (int)(e & (B_N - 1));
        __syncthreads();
        for (int i = tid; i < D_K; i += 256) xs[i] = x[(size_t)r * D_K + i];
        __syncthreads();
        float a0 = 0.f, a1 = 0.f, a2 = 0.f, a3 = 0.f;
        const int g3 = (tid < C_N - 768);
        const int c3 = g3 ? tid + 768 : tid;
        const float* wb = W + (size_t)m * D_K * C_N;
        for (int k = 0; k < D_K; ++k) {
            float xv = xs[k];
            const float* wr_ = wb + (size_t)k * C_N;
            a0 = fmaf(xv, wr_[tid], a0);
            a1 = fmaf(xv, wr_[tid + 256], a1);
            a2 = fmaf(xv, wr_[tid + 512], a2);
            a3 = fmaf(xv, wr_[c3], a3);
        }
        const float* bb = bias + m * C_N;
        float best = a0 + bb[tid]; int bi = tid;
        float v = a1 + bb[tid + 256]; if (v > best) { best = v; bi = tid + 256; }
        v = a2 + bb[tid + 512]; if (v > best) { best = v; bi = tid + 512; }
        if (g3) { v = a3 + bb[tid + 768]; if (v > best) { best = v; bi = tid + 768; } }
#pragma unroll
        for (int mask = 1; mask < 64; mask <<= 1) {
            float ov = __shfl_xor(best, mask); int oi = __shfl_xor(bi, mask);
            if (ov > best || (ov == best && oi < bi)) { best = ov; bi = oi; }
        }
        if (lane == 0) { rv[wv] = best; ri[wv] = bi; }
        __syncthreads();
        if (tid == 0) {
            for (int q = 1; q < 4; ++q)
                if (rv[q] > best || (rv[q] == best && ri[q] < bi)) { best = rv[q]; bi = ri[q]; }
            wout[e] = (unsigned)bi;
        }
    }
}

__global__ __launch_bounds__(256) void ve_zero_out(float* __restrict__ out, int n4) {
    int i = blockIdx.x * blockDim.x + threadIdx.x;
    const float4 z = make_float4(0.f, 0.f, 0.f, 0.f);
    for (; i < n4; i += gridDim.x * blockDim.x)
        reinterpret_cast<float4*>(out)[i] = z;
}

__global__ __launch_bounds__(256) void ve_vote2(const unsigned int* __restrict__ wout,
        const float* __restrict__ coefs, float* __restrict__ out) {
    int r = blockIdx.x * 256 + threadIdx.x;
#pragma unroll
    for (int m = 0; m < M_N; ++m)
        out[(size_t)r * C_N + wout[m * B_N + r]] += coefs[m] * 0.125f;
}

// ================= fallback: proven round-1 fp32 path =================

#define TM 128
#define TN 128
#define TK 32
#define CT 8

__global__ __launch_bounds__(256) void ve_gemm_argmax_fb(
        const float* __restrict__ x, const float* __restrict__ W,
        const float* __restrict__ bias, float2* __restrict__ part) {
    __shared__ float xs[TK][TM + 1];
    __shared__ float ws[TK][TN];
    const int ct = blockIdx.x, rt = blockIdx.y, m = blockIdx.z;
    const int tid = threadIdx.x;
    const int tx = tid & 15, ty = tid >> 4;
    const int r0 = rt * TM, c0 = ct * TN;
    float acc[8][8];
#pragma unroll
    for (int i = 0; i < 8; i++)
#pragma unroll
        for (int j = 0; j < 8; j++) acc[i][j] = 0.f;
    const float* xbase = x + (size_t)r0 * D_K;
    for (int kt = 0; kt < D_K; kt += TK) {
#pragma unroll
        for (int i = 0; i < 4; i++) {
            int l = tid + i * 256;
            int row = l >> 3, kq = l & 7;
            float4 v = *reinterpret_cast<const float4*>(xbase + (size_t)row * D_K + kt + kq * 4);
            int kk = kq * 4;
            xs[kk + 0][row] = v.x; xs[kk + 1][row] = v.y;
            xs[kk + 2][row] = v.z; xs[kk + 3][row] = v.w;
        }
#pragma unroll
        for (int i = 0; i < 4; i++) {
            int l = tid + i * 256;
            int kk = l >> 5, cq = l & 31;
            int c = c0 + cq * 4;
            const float* p = W + ((size_t)(m * D_K + kt + kk)) * C_N + c;
            float4 v;
            if (c + 3 < C_N) v = *reinterpret_cast<const float4*>(p);
            else {
                v.x = (c + 0 < C_N) ? p[0] : 0.f; v.y = (c + 1 < C_N) ? p[1] : 0.f;
                v.z = (c + 2 < C_N) ? p[2] : 0.f; v.w = (c + 3 < C_N) ? p[3] : 0.f;
            }
            ws[kk][cq * 4 + 0] = v.x; ws[kk][cq * 4 + 1] = v.y;
            ws[kk][cq * 4 + 2] = v.z; ws[kk][cq * 4 + 3] = v.w;
        }
        __syncthreads();
        for (int kk = 0; kk < TK; kk++) {
            float a[8], bb[8];
#pragma unroll
            for (int i = 0; i < 8; i++) a[i] = xs[kk][ty + i * 16];
#pragma unroll
            for (int j = 0; j < 8; j++) bb[j] = ws[kk][tx + j * 16];
#pragma unroll
            for (int i = 0; i < 8; i++)
#pragma unroll
                for (int j = 0; j < 8; j++) acc[i][j] += a[i] * bb[j];
        }
        __syncthreads();
    }
    const float NEG_INF = -__builtin_huge_valf();
    float bv[8]; int cv[8];
#pragma unroll
    for (int j = 0; j < 8; j++) {
        int c = c0 + tx + j * 16;
        cv[j] = c;
        bv[j] = (c < C_N) ? bias[m * C_N + c] : 0.f;
    }
#pragma unroll
    for (int i = 0; i < 8; i++) {
        int r = r0 + ty + i * 16;
        float best = NEG_INF; int bidx = 0x7fffffff;
#pragma unroll
        for (int j = 0; j < 8; j++) {
            int c = cv[j];
            float v = (c < C_N) ? (acc[i][j] + bv[j]) : NEG_INF;
            if (v > best || (v == best && c < bidx)) { best = v; bidx = c; }
        }
#pragma unroll
        for (int mask = 1; mask < 16; mask <<= 1) {
            float ov = __shfl_xor(best, mask);
            int oi = __shfl_xor(bidx, mask);
            if (ov > best || (ov == best && oi < bidx)) { best = ov; bidx = oi; }
        }
        if (tx == 0) part[((size_t)m * B_N + r) * CT + ct] = make_float2(best, __int_as_float(bidx));
    }
}

__global__ __launch_bounds__(256) void ve_vote_fb(const float2* __restrict__ part,
        const float* __restrict__ coefs, float* __restrict__ out) {
    int r = blockIdx.x * blockDim.x + threadIdx.x;
    if (r >= B_N) return;
    const float NEG_INF = -__builtin_huge_valf();
#pragma unroll
    for (int m = 0; m < M_N; m++) {
        float best = NEG_INF; int bidx = 0x7fffffff;
#pragma unroll
        for (int ct = 0; ct < CT; ct++) {
            float2 p = part[((size_t)m * B_N + r) * CT + ct];
            int oi = __float_as_int(p.y);
            if (p.x > best || (p.x == best && oi < bidx)) { best = p.x; bidx = oi; }
        }
        out[(size_t)r * C_N + bidx] += coefs[m] * 0.125f;
    }
}

// ================= launcher =================

extern "C" void kernel_launch(void* const* d_in, const int* in_sizes, int n_in,
                              void* d_out, int out_size, void* d_ws, size_t ws_size,
                              hipStream_t stream) {
    const float* x     = (const float*)d_in[0];
    const float* W     = (const float*)d_in[1];
    const float* bias  = (const float*)d_in[2];
    const float* coefs = (const float*)d_in[3];
    float* out = (float*)d_out;

    const size_t NEED = (57ull << 20) + 4096;
    if (ws_size >= NEED) {
        char* ws = (char*)d_ws;
        unsigned short* Xh   = (unsigned short*)(ws);                  // 16 MiB
        unsigned short* Xl   = (unsigned short*)(ws + (16ull << 20));  // 16 MiB
        unsigned short* WhT  = (unsigned short*)(ws + (32ull << 20));  //  8 MiB
        unsigned short* WlT  = (unsigned short*)(ws + (40ull << 20));  //  8 MiB
        float4*         part = (float4*)(ws + (48ull << 20));          //  8 MiB
        unsigned int*   wout = (unsigned int*)(ws + (56ull << 20));    // 512 KiB
        unsigned int*   list = (unsigned int*)(ws + (56ull << 20) + (512ull << 10));
        unsigned int*   cnt  = (unsigned int*)(ws + (57ull << 20));

        ve_conv_x<<<8192, 256, 0, stream>>>(x, Xh, Xl, cnt);
        ve_conv_w<<<dim3(16, 8, 8), 256, 0, stream>>>(W, WhT, WlT);
        ve_gemm8<<<dim3(64, 4, 8), 512, 0, stream>>>(Xh, Xl, WhT, WlT, bias, part);
        ve_flag4<<<64, 256, 0, stream>>>(part, wout, list, cnt);
        ve_exact<<<128, 256, 0, stream>>>(x, W, bias, list, cnt, wout);
        ve_zero_out<<<2048, 256, 0, stream>>>(out, B_N * C_N / 4);
        ve_vote2<<<64, 256, 0, stream>>>(wout, coefs, out);
    } else {
        float2* part = (float2*)d_ws;
        ve_zero_out<<<2048, 256, 0, stream>>>(out, B_N * C_N / 4);
        dim3 grid(CT, B_N / TM, M_N);
        ve_gemm_argmax_fb<<<grid, 256, 0, stream>>>(x, W, bias, part);
        ve_vote_fb<<<(B_N + 255) / 256, 256, 0, stream>>>(part, coefs, out);
    }
}

// Round 8
// 433.682 us; speedup vs baseline: 1.7680x; 1.6369x over previous
//
#include <hip/hip_runtime.h>

#define B_N 16384
#define D_K 512
#define C_N 1000
#define CP 1024
#define M_N 8
#define GAP_EPS 1e-3f

typedef __attribute__((ext_vector_type(8))) _Float16 f16x8;
typedef __attribute__((ext_vector_type(4))) float f32x4;

typedef const __attribute__((address_space(1))) unsigned int* gptr_t;
typedef __attribute__((address_space(3))) unsigned int* lptr_t;

__device__ __forceinline__ void gload16(const void* g, void* l) {
    __builtin_amdgcn_global_load_lds((gptr_t)g, (lptr_t)l, 16, 0, 0);
}

__device__ __forceinline__ unsigned short h16(float f) {
    _Float16 h = (_Float16)f;   // v_cvt_f16_f32, RTN
    return *(unsigned short*)&h;
}

// ---------------- conversion kernels ----------------

__global__ __launch_bounds__(256) void ve_conv_x16(const float* __restrict__ x,
        unsigned short* __restrict__ xf, unsigned int* __restrict__ cnts) {
    int i = blockIdx.x * 256 + threadIdx.x;
    if (blockIdx.x == 0 && threadIdx.x < M_N) cnts[threadIdx.x] = 0u;
    float4 v = reinterpret_cast<const float4*>(x)[i];
    ushort4 h;
    h.x = h16(v.x); h.y = h16(v.y); h.z = h16(v.z); h.w = h16(v.w);
    reinterpret_cast<ushort4*>(xf)[i] = h;
}

// W [8][512][1000] fp32 -> WT16 [8][1024][512] fp16 (transposed, c-padded 0)
__global__ __launch_bounds__(256) void ve_conv_w16(const float* __restrict__ W,
        unsigned short* __restrict__ wt) {
    __shared__ float t[64][65];
    const int m = blockIdx.z, k0 = blockIdx.y * 64, c0 = blockIdx.x * 64;
    const int tid = threadIdx.x;
#pragma unroll
    for (int p = 0; p < 16; ++p) {
        int idx = p * 256 + tid;
        int kk = idx >> 6, cc = idx & 63;
        int c = c0 + cc;
        t[kk][cc] = (c < C_N) ? W[((size_t)m * D_K + k0 + kk) * C_N + c] : 0.f;
    }
    __syncthreads();
#pragma unroll
    for (int p = 0; p < 4; ++p) {
        int idx = p * 256 + tid;
        int cc = idx >> 4, kq = idx & 15;
        ushort4 h;
        h.x = h16(t[kq * 4 + 0][cc]); h.y = h16(t[kq * 4 + 1][cc]);
        h.z = h16(t[kq * 4 + 2][cc]); h.w = h16(t[kq * 4 + 3][cc]);
        size_t o = ((size_t)m * CP + c0 + cc) * D_K + k0 + kq * 4;
        *reinterpret_cast<ushort4*>(wt + o) = h;
    }
}

// ---------------- 1-term fp16 MFMA GEMM, 128x128 tile, 4 waves ----------------
// m97-family structure: single LDS buffer, stage -> sync -> read+MFMA -> sync.
// LDS layout (round-4-verified): line L (128B) holds rows 2L,2L+1; logical slot
// s3=(row&1)*4+kg stored at s3^(L&7); inverse pre-applied on global source.

__global__ __launch_bounds__(256, 4) void ve_gemm16(
        const unsigned short* __restrict__ Xf, const unsigned short* __restrict__ WT,
        const float* __restrict__ bias, float4* __restrict__ part) {
    __shared__ unsigned short At[4096];   // 8 KB: 128 rows x 32 k
    __shared__ unsigned short Bt[4096];   // 8 KB: 128 cols x 32 k
    __shared__ float4 wtop[128][2];
    __shared__ float bs[128];

    const int tid = threadIdx.x;
    const int l = tid & 63, w = tid >> 6;
    const int wr = w >> 1, wc = w & 1;        // 2x2 waves; per-wave C = 64x64
    const int l15 = l & 15, kg = l >> 4;
    const int rt = blockIdx.x, ct = blockIdx.y, mb = blockIdx.z;
    const int r0 = rt * 128, c0 = ct * 128;

    if (tid < 128) {
        int c = c0 + tid;
        bs[tid] = (c < C_N) ? bias[mb * C_N + c] : -1e30f;
    }

    // staging lane constants (inverse swizzle, round-4-verified)
    const int lhi = l >> 3, llo = l & 7;
    const int s3g = llo ^ lhi;
    const int srow16 = (lhi << 1) | (s3g >> 2);
    const int kgs = (s3g & 3) * 8;            // halves

    const unsigned short* xA0 = Xf + (size_t)(r0 +      w * 16 + srow16) * D_K + kgs;
    const unsigned short* xA1 = Xf + (size_t)(r0 + 64 + w * 16 + srow16) * D_K + kgs;
    const unsigned short* xB0 = WT + (size_t)(mb * CP + c0 +      w * 16 + srow16) * D_K + kgs;
    const unsigned short* xB1 = WT + (size_t)(mb * CP + c0 + 64 + w * 16 + srow16) * D_K + kgs;
    unsigned short* dA0 = At + tid * 8;
    unsigned short* dA1 = At + 2048 + tid * 8;
    unsigned short* dB0 = Bt + tid * 8;
    unsigned short* dB1 = Bt + 2048 + tid * 8;

    // fragment read pointers (loop-invariant; swizzled offsets, round-4 formula)
    auto ldsoff = [&](int row, int kc) {
        return (row >> 1) * 64 + (((((row & 1) << 2) | kc) ^ ((row >> 1) & 7)) * 8);
    };
    const char* aP[4]; const char* bP[4];
#pragma unroll
    for (int i = 0; i < 4; ++i) {
        aP[i] = (const char*)At + 2 * ldsoff(wr * 64 + i * 16 + l15, kg);
        bP[i] = (const char*)Bt + 2 * ldsoff(wc * 64 + i * 16 + l15, kg);
    }

    f32x4 acc[4][4];
#pragma unroll
    for (int i = 0; i < 4; ++i)
#pragma unroll
        for (int j = 0; j < 4; ++j) acc[i][j] = (f32x4){0.f, 0.f, 0.f, 0.f};

#pragma unroll
    for (int t = 0; t < 16; ++t) {
        // stage tile t (WAR-safe: previous tile's LDS reads completed before
        // the trailing __syncthreads of iteration t-1)
        gload16(xA0 + t * 32, dA0);
        gload16(xA1 + t * 32, dA1);
        gload16(xB0 + t * 32, dB0);
        gload16(xB1 + t * 32, dB1);
        __syncthreads();   // drains vmcnt(0): tile t fully in LDS

        f16x8 af[4], bf[4];
#pragma unroll
        for (int i = 0; i < 4; ++i) af[i] = *reinterpret_cast<const f16x8*>(aP[i]);
#pragma unroll
        for (int j = 0; j < 4; ++j) bf[j] = *reinterpret_cast<const f16x8*>(bP[j]);
#pragma unroll
        for (int i = 0; i < 4; ++i)
#pragma unroll
            for (int j = 0; j < 4; ++j)
                acc[i][j] = __builtin_amdgcn_mfma_f32_16x16x32_f16(af[i], bf[j], acc[i][j], 0, 0, 0);
        __syncthreads();   // all LDS reads of tile t done before next stage
    }

    // ---------------- epilogue: bias + per-wave top-2 over its 64 cols ----------------
    float bsv[4]; int cg[4];
#pragma unroll
    for (int j = 0; j < 4; ++j) {
        int cl = wc * 64 + j * 16 + l15;
        bsv[j] = bs[cl];
        cg[j] = c0 + cl;
    }
#pragma unroll
    for (int i = 0; i < 4; ++i) {
#pragma unroll
        for (int reg = 0; reg < 4; ++reg) {
            float v1 = acc[i][0][reg] + bsv[0]; int i1 = cg[0];
            float v2 = -1e30f; int i2 = 0x7fffffff;
#pragma unroll
            for (int j = 1; j < 4; ++j) {
                float v = acc[i][j][reg] + bsv[j]; int cc = cg[j];
                if (v > v1 || (v == v1 && cc < i1)) { v2 = v1; i2 = i1; v1 = v; i1 = cc; }
                else if (v > v2 || (v == v2 && cc < i2)) { v2 = v; i2 = cc; }
            }
#pragma unroll
            for (int mask = 1; mask < 16; mask <<= 1) {
                float ov1 = __shfl_xor(v1, mask); int oi1 = __shfl_xor(i1, mask);
                float ov2 = __shfl_xor(v2, mask); int oi2 = __shfl_xor(i2, mask);
                if (ov1 > v1 || (ov1 == v1 && oi1 < i1)) {
                    float nv2 = v1; int ni2 = i1;
                    if (ov2 > nv2 || (ov2 == nv2 && oi2 < ni2)) { nv2 = ov2; ni2 = oi2; }
                    v1 = ov1; i1 = oi1; v2 = nv2; i2 = ni2;
                } else if (ov1 > v2 || (ov1 == v2 && oi1 < i2)) { v2 = ov1; i2 = oi1; }
            }
            if (l15 == 0) {
                int row = wr * 64 + i * 16 + (l >> 4) * 4 + reg;
                wtop[row][wc] = make_float4(v1, __int_as_float(i1), v2, __int_as_float(i2));
            }
        }
    }
    __syncthreads();
    if (tid < 128) {
        float v1 = -1e30f; int i1 = 0x7fffffff;
        float v2 = -1e30f; int i2 = 0x7fffffff;
#pragma unroll
        for (int s = 0; s < 2; ++s) {
            float4 o = wtop[tid][s];
            float ov1 = o.x; int oi1 = __float_as_int(o.y);
            float ov2 = o.z; int oi2 = __float_as_int(o.w);
            if (ov1 > v1 || (ov1 == v1 && oi1 < i1)) {
                float nv2 = v1; int ni2 = i1;
                if (ov2 > nv2 || (ov2 == nv2 && oi2 < ni2)) { nv2 = ov2; ni2 = oi2; }
                v1 = ov1; i1 = oi1; v2 = nv2; i2 = ni2;
            } else if (ov1 > v2 || (ov1 == v2 && oi1 < i2)) { v2 = ov1; i2 = oi1; }
        }
        part[((size_t)mb * B_N + r0 + tid) * 8 + ct] =
            make_float4(v1, __int_as_float(i1), v2, __int_as_float(i2));
    }
}

// -------- merge 8 C-tiles, write approx argmax, flag small-gap rows per model --------

__global__ __launch_bounds__(256) void ve_flag8(const float4* __restrict__ part,
        unsigned int* __restrict__ wout, unsigned int* __restrict__ rlist,
        unsigned int* __restrict__ cnts) {
    int r = blockIdx.x * 256 + threadIdx.x;
#pragma unroll
    for (int m = 0; m < M_N; ++m) {
        float v1 = -1e30f; int i1 = 0x7fffffff;
        float v2 = -1e30f; int i2 = 0x7fffffff;
#pragma unroll
        for (int t = 0; t < 8; ++t) {
            float4 o = part[((size_t)m * B_N + r) * 8 + t];
            float ov1 = o.x; int oi1 = __float_as_int(o.y);
            float ov2 = o.z; int oi2 = __float_as_int(o.w);
            if (ov1 > v1 || (ov1 == v1 && oi1 < i1)) {
                float nv2 = v1; int ni2 = i1;
                if (ov2 > nv2 || (ov2 == nv2 && oi2 < ni2)) { nv2 = ov2; ni2 = oi2; }
                v1 = ov1; i1 = oi1; v2 = nv2; i2 = ni2;
            } else if (ov1 > v2 || (ov1 == v2 && oi1 < i2)) { v2 = ov1; i2 = oi1; }
        }
        wout[m * B_N + r] = (unsigned)i1;
        if (v1 - v2 <= GAP_EPS) {
            unsigned pos = atomicAdd(&cnts[m], 1u);
            rlist[m * B_N + pos] = (unsigned)r;
        }
    }
}

// -------- grouped exact pass: round-1 fp32 kernel over gathered flagged rows --------
// Identical serial-k FMA accumulation to the (numpy-matching) round-1 kernel.

__global__ __launch_bounds__(256) void ve_exact_g(
        const float* __restrict__ x, const float* __restrict__ W,
        const float* __restrict__ bias, const unsigned int* __restrict__ rlist,
        const unsigned int* __restrict__ cnts, float2* __restrict__ part2) {
    __shared__ float xs[32][129];
    __shared__ float wsm[32][128];
    __shared__ int rg[128];
    const int ct = blockIdx.x, m = blockIdx.z;
    const int tid = threadIdx.x;
    const int tx = tid & 15, ty = tid >> 4;
    const int c0 = ct * 128;
    const unsigned nm = cnts[m];

    for (unsigned rb = blockIdx.y; rb * 128 < nm; rb += gridDim.y) {
        __syncthreads();
        if (tid < 128) {
            unsigned idx = rb * 128 + tid;
            rg[tid] = (idx < nm) ? (int)rlist[m * B_N + idx] : 0;
        }
        __syncthreads();

        float acc[8][8];
#pragma unroll
        for (int i = 0; i < 8; i++)
#pragma unroll
            for (int j = 0; j < 8; j++) acc[i][j] = 0.f;

        for (int kt = 0; kt < D_K; kt += 32) {
#pragma unroll
            for (int i = 0; i < 4; i++) {
                int li = tid + i * 256;
                int row = li >> 3, kq = li & 7;
                float4 v = *reinterpret_cast<const float4*>(
                        x + (size_t)rg[row] * D_K + kt + kq * 4);
                int kk = kq * 4;
                xs[kk + 0][row] = v.x; xs[kk + 1][row] = v.y;
                xs[kk + 2][row] = v.z; xs[kk + 3][row] = v.w;
            }
#pragma unroll
            for (int i = 0; i < 4; i++) {
                int li = tid + i * 256;
                int kk = li >> 5, cq = li & 31;
                int c = c0 + cq * 4;
                const float* p = W + ((size_t)(m * D_K + kt + kk)) * C_N + c;
                float4 v;
                if (c + 3 < C_N) v = *reinterpret_cast<const float4*>(p);
                else {
                    v.x = (c + 0 < C_N) ? p[0] : 0.f; v.y = (c + 1 < C_N) ? p[1] : 0.f;
                    v.z = (c + 2 < C_N) ? p[2] : 0.f; v.w = (c + 3 < C_N) ? p[3] : 0.f;
                }
                wsm[kk][cq * 4 + 0] = v.x; wsm[kk][cq * 4 + 1] = v.y;
                wsm[kk][cq * 4 + 2] = v.z; wsm[kk][cq * 4 + 3] = v.w;
            }
            __syncthreads();
            for (int kk = 0; kk < 32; kk++) {
                float a[8], bb[8];
#pragma unroll
                for (int i = 0; i < 8; i++) a[i] = xs[kk][ty + i * 16];
#pragma unroll
                for (int j = 0; j < 8; j++) bb[j] = wsm[kk][tx + j * 16];
#pragma unroll
                for (int i = 0; i < 8; i++)
#pragma unroll
                    for (int j = 0; j < 8; j++) acc[i][j] += a[i] * bb[j];
            }
            __syncthreads();
        }

        const float NEG_INF = -__builtin_huge_valf();
        float bv[8]; int cv[8];
#pragma unroll
        for (int j = 0; j < 8; j++) {
            int c = c0 + tx + j * 16;
            cv[j] = c;
            bv[j] = (c < C_N) ? bias[m * C_N + c] : 0.f;
        }
#pragma unroll
        for (int i = 0; i < 8; i++) {
            float best = NEG_INF; int bidx = 0x7fffffff;
#pragma unroll
            for (int j = 0; j < 8; j++) {
                int c = cv[j];
                float v = (c < C_N) ? (acc[i][j] + bv[j]) : NEG_INF;
                if (v > best || (v == best && c < bidx)) { best = v; bidx = c; }
            }
#pragma unroll
            for (int mask = 1; mask < 16; mask <<= 1) {
                float ov = __shfl_xor(best, mask);
                int oi = __shfl_xor(bidx, mask);
                if (ov > best || (ov == best && oi < bidx)) { best = ov; bidx = oi; }
            }
            unsigned slot = rb * 128 + ty + i * 16;
            if (tx == 0 && slot < nm)
                part2[((size_t)m * B_N + slot) * 8 + ct] = make_float2(best, __int_as_float(bidx));
        }
    }
}

// merge exact per-ct partials -> final argmax for flagged rows
__global__ __launch_bounds__(256) void ve_merge_x(const float2* __restrict__ part2,
        const unsigned int* __restrict__ rlist, const unsigned int* __restrict__ cnts,
        unsigned int* __restrict__ wout) {
    int gid = blockIdx.x * 256 + threadIdx.x;
    int m = gid >> 14, s = gid & (B_N - 1);
    if (s < (int)cnts[m]) {
        const float NEG_INF = -__builtin_huge_valf();
        float best = NEG_INF; int bidx = 0x7fffffff;
#pragma unroll
        for (int ctt = 0; ctt < 8; ctt++) {
            float2 p = part2[((size_t)m * B_N + s) * 8 + ctt];
            int oi = __float_as_int(p.y);
            if (p.x > best || (p.x == best && oi < bidx)) { best = p.x; bidx = oi; }
        }
        wout[m * B_N + rlist[m * B_N + s]] = (unsigned)bidx;
    }
}

__global__ __launch_bounds__(256) void ve_zero_out(float* __restrict__ out, int n4) {
    int i = blockIdx.x * blockDim.x + threadIdx.x;
    const float4 z = make_float4(0.f, 0.f, 0.f, 0.f);
    for (; i < n4; i += gridDim.x * blockDim.x)
        reinterpret_cast<float4*>(out)[i] = z;
}

__global__ __launch_bounds__(256) void ve_vote2(const unsigned int* __restrict__ wout,
        const float* __restrict__ coefs, float* __restrict__ out) {
    int r = blockIdx.x * 256 + threadIdx.x;
#pragma unroll
    for (int m = 0; m < M_N; ++m)
        out[(size_t)r * C_N + wout[m * B_N + r]] += coefs[m] * 0.125f;
}

// ================= fallback: proven round-1 fp32 path =================

#define TM 128
#define TN 128
#define TK 32
#define CT 8

__global__ __launch_bounds__(256) void ve_gemm_argmax_fb(
        const float* __restrict__ x, const float* __restrict__ W,
        const float* __restrict__ bias, float2* __restrict__ part) {
    __shared__ float xs[TK][TM + 1];
    __shared__ float ws[TK][TN];
    const int ct = blockIdx.x, rt = blockIdx.y, m = blockIdx.z;
    const int tid = threadIdx.x;
    const int tx = tid & 15, ty = tid >> 4;
    const int r0 = rt * TM, c0 = ct * TN;
    float acc[8][8];
#pragma unroll
    for (int i = 0; i < 8; i++)
#pragma unroll
        for (int j = 0; j < 8; j++) acc[i][j] = 0.f;
    const float* xbase = x + (size_t)r0 * D_K;
    for (int kt = 0; kt < D_K; kt += TK) {
#pragma unroll
        for (int i = 0; i < 4; i++) {
            int li = tid + i * 256;
            int row = li >> 3, kq = li & 7;
            float4 v = *reinterpret_cast<const float4*>(xbase + (size_t)row * D_K + kt + kq * 4);
            int kk = kq * 4;
            xs[kk + 0][row] = v.x; xs[kk + 1][row] = v.y;
            xs[kk + 2][row] = v.z; xs[kk + 3][row] = v.w;
        }
#pragma unroll
        for (int i = 0; i < 4; i++) {
            int li = tid + i * 256;
            int kk = li >> 5, cq = li & 31;
            int c = c0 + cq * 4;
            const float* p = W + ((size_t)(m * D_K + kt + kk)) * C_N + c;
            float4 v;
            if (c + 3 < C_N) v = *reinterpret_cast<const float4*>(p);
            else {
                v.x = (c + 0 < C_N) ? p[0] : 0.f; v.y = (c + 1 < C_N) ? p[1] : 0.f;
                v.z = (c + 2 < C_N) ? p[2] : 0.f; v.w = (c + 3 < C_N) ? p[3] : 0.f;
            }
            ws[kk][cq * 4 + 0] = v.x; ws[kk][cq * 4 + 1] = v.y;
            ws[kk][cq * 4 + 2] = v.z; ws[kk][cq * 4 + 3] = v.w;
        }
        __syncthreads();
        for (int kk = 0; kk < TK; kk++) {
            float a[8], bb[8];
#pragma unroll
            for (int i = 0; i < 8; i++) a[i] = xs[kk][ty + i * 16];
#pragma unroll
            for (int j = 0; j < 8; j++) bb[j] = ws[kk][tx + j * 16];
#pragma unroll
            for (int i = 0; i < 8; i++)
#pragma unroll
                for (int j = 0; j < 8; j++) acc[i][j] += a[i] * bb[j];
        }
        __syncthreads();
    }
    const float NEG_INF = -__builtin_huge_valf();
    float bv[8]; int cv[8];
#pragma unroll
    for (int j = 0; j < 8; j++) {
        int c = c0 + tx + j * 16;
        cv[j] = c;
        bv[j] = (c < C_N) ? bias[m * C_N + c] : 0.f;
    }
#pragma unroll
    for (int i = 0; i < 8; i++) {
        int r = r0 + ty + i * 16;
        float best = NEG_INF; int bidx = 0x7fffffff;
#pragma unroll
        for (int j = 0; j < 8; j++) {
            int c = cv[j];
            float v = (c < C_N) ? (acc[i][j] + bv[j]) : NEG_INF;
            if (v > best || (v == best && c < bidx)) { best = v; bidx = c; }
        }
#pragma unroll
        for (int mask = 1; mask < 16; mask <<= 1) {
            float ov = __shfl_xor(best, mask);
            int oi = __shfl_xor(bidx, mask);
            if (ov > best || (ov == best && oi < bidx)) { best = ov; bidx = oi; }
        }
        if (tx == 0) part[((size_t)m * B_N + r) * CT + ct] = make_float2(best, __int_as_float(bidx));
    }
}

__global__ __launch_bounds__(256) void ve_vote_fb(const float2* __restrict__ part,
        const float* __restrict__ coefs, float* __restrict__ out) {
    int r = blockIdx.x * blockDim.x + threadIdx.x;
    if (r >= B_N) return;
    const float NEG_INF = -__builtin_huge_valf();
#pragma unroll
    for (int m = 0; m < M_N; m++) {
        float best = NEG_INF; int bidx = 0x7fffffff;
#pragma unroll
        for (int ctt = 0; ctt < CT; ctt++) {
            float2 p = part[((size_t)m * B_N + r) * CT + ctt];
            int oi = __float_as_int(p.y);
            if (p.x > best || (p.x == best && oi < bidx)) { best = p.x; bidx = oi; }
        }
        out[(size_t)r * C_N + bidx] += coefs[m] * 0.125f;
    }
}

// ================= launcher =================

extern "C" void kernel_launch(void* const* d_in, const int* in_sizes, int n_in,
                              void* d_out, int out_size, void* d_ws, size_t ws_size,
                              hipStream_t stream) {
    const float* x     = (const float*)d_in[0];
    const float* W     = (const float*)d_in[1];
    const float* bias  = (const float*)d_in[2];
    const float* coefs = (const float*)d_in[3];
    float* out = (float*)d_out;

    const size_t NEED = (57ull << 20) + 4096;
    if (ws_size >= NEED) {
        char* ws = (char*)d_ws;
        unsigned short* Xf    = (unsigned short*)(ws);                   // 16 MiB
        unsigned short* WT16  = (unsigned short*)(ws + (16ull << 20));   //  8 MiB
        float4*         part  = (float4*)(ws + (24ull << 20));           // 16 MiB
        float2*         part2 = (float2*)(ws + (24ull << 20));           //  8 MiB (reuses part after flag)
        unsigned int*   wout  = (unsigned int*)(ws + (40ull << 20));     // 512 KiB
        unsigned int*   rlist = (unsigned int*)(ws + (40ull << 20) + (512ull << 10)); // 512 KiB
        unsigned int*   cnts  = (unsigned int*)(ws + (41ull << 20));     // 32 B

        ve_conv_x16<<<8192, 256, 0, stream>>>(x, Xf, cnts);
        ve_conv_w16<<<dim3(16, 8, 8), 256, 0, stream>>>(W, WT16);
        ve_gemm16<<<dim3(128, 8, 8), 256, 0, stream>>>(Xf, WT16, bias, part);
        ve_flag8<<<64, 256, 0, stream>>>(part, wout, rlist, cnts);
        ve_exact_g<<<dim3(8, 4, 8), 256, 0, stream>>>(x, W, bias, rlist, cnts, part2);
        ve_merge_x<<<512, 256, 0, stream>>>(part2, rlist, cnts, wout);
        ve_zero_out<<<2048, 256, 0, stream>>>(out, B_N * C_N / 4);
        ve_vote2<<<64, 256, 0, stream>>>(wout, coefs, out);
    } else {
        float2* partf = (float2*)d_ws;
        ve_zero_out<<<2048, 256, 0, stream>>>(out, B_N * C_N / 4);
        dim3 grid(CT, B_N / TM, M_N);
        ve_gemm_argmax_fb<<<grid, 256, 0, stream>>>(x, W, bias, partf);
        ve_vote_fb<<<(B_N + 255) / 256, 256, 0, stream>>>(partf, coefs, out);
    }
}

// Round 9
// 431.139 us; speedup vs baseline: 1.7785x; 1.0059x over previous
//
#include <hip/hip_runtime.h>

#define B_N 16384
#define D_K 512
#define C_N 1000
#define CP 1024
#define M_N 8
#define GAP_EPS 1e-3f

typedef __attribute__((ext_vector_type(8))) _Float16 f16x8;
typedef __attribute__((ext_vector_type(4))) float f32x4;

typedef const __attribute__((address_space(1))) unsigned int* gptr_t;
typedef __attribute__((address_space(3))) unsigned int* lptr_t;

__device__ __forceinline__ void gload16(const void* g, void* l) {
    __builtin_amdgcn_global_load_lds((gptr_t)g, (lptr_t)l, 16, 0, 0);
}

__device__ __forceinline__ unsigned short h16(float f) {
    _Float16 h = (_Float16)f;   // v_cvt_f16_f32, RTN
    return *(unsigned short*)&h;
}

// ---------------- conversion kernels ----------------

__global__ __launch_bounds__(256) void ve_conv_x16(const float* __restrict__ x,
        unsigned short* __restrict__ xf, unsigned int* __restrict__ cnts) {
    int i = blockIdx.x * 256 + threadIdx.x;
    if (blockIdx.x == 0 && threadIdx.x < M_N) cnts[threadIdx.x] = 0u;
    float4 v = reinterpret_cast<const float4*>(x)[i];
    ushort4 h;
    h.x = h16(v.x); h.y = h16(v.y); h.z = h16(v.z); h.w = h16(v.w);
    reinterpret_cast<ushort4*>(xf)[i] = h;
}

// W [8][512][1000] fp32 -> WT16 [8][1024][512] fp16 (transposed, c-padded 0)
__global__ __launch_bounds__(256) void ve_conv_w16(const float* __restrict__ W,
        unsigned short* __restrict__ wt) {
    __shared__ float t[64][65];
    const int m = blockIdx.z, k0 = blockIdx.y * 64, c0 = blockIdx.x * 64;
    const int tid = threadIdx.x;
#pragma unroll
    for (int p = 0; p < 16; ++p) {
        int idx = p * 256 + tid;
        int kk = idx >> 6, cc = idx & 63;
        int c = c0 + cc;
        t[kk][cc] = (c < C_N) ? W[((size_t)m * D_K + k0 + kk) * C_N + c] : 0.f;
    }
    __syncthreads();
#pragma unroll
    for (int p = 0; p < 4; ++p) {
        int idx = p * 256 + tid;
        int cc = idx >> 4, kq = idx & 15;
        ushort4 h;
        h.x = h16(t[kq * 4 + 0][cc]); h.y = h16(t[kq * 4 + 1][cc]);
        h.z = h16(t[kq * 4 + 2][cc]); h.w = h16(t[kq * 4 + 3][cc]);
        size_t o = ((size_t)m * CP + c0 + cc) * D_K + k0 + kq * 4;
        *reinterpret_cast<ushort4*>(wt + o) = h;
    }
}

// ---------------- 1-term fp16 MFMA GEMM, 128x128 tile, 4 waves, BK=64 ----------------
// m97-family 2-barrier loop, 8 K-iterations. Each BK=64 tile = two 32-k
// sub-tiles, each stored in the round-8-verified swizzled layout (lines of
// 128B holding row pairs; slot s3=(row&1)*4+kc stored at s3^(L&7); inverse
// pre-applied on the global source). LDS = exactly 32 KB (At+Bt); the
// epilogue wtop buffer overlays dead At -> 5 blocks/CU.

__global__ __launch_bounds__(256, 4) void ve_gemm16(
        const unsigned short* __restrict__ Xf, const unsigned short* __restrict__ WT,
        const float* __restrict__ bias, float4* __restrict__ part) {
    __shared__ unsigned short At[8192];   // 16 KB: [subk][128 rows x 32 k]
    __shared__ unsigned short Bt[8192];   // 16 KB

    const int tid = threadIdx.x;
    const int l = tid & 63, w = tid >> 6;
    const int wr = w >> 1, wc = w & 1;        // 2x2 waves; per-wave C = 64x64
    const int l15 = l & 15, kg = l >> 4;
    const int rt = blockIdx.x, ct = blockIdx.y, mb = blockIdx.z;
    const int r0 = rt * 128, c0 = ct * 128;

    // staging lane constants (round-8-verified inverse swizzle)
    const int lhi = l >> 3, llo = l & 7;
    const int s3g = llo ^ lhi;
    const int srow16 = (lhi << 1) | (s3g >> 2);
    const int kgs = (s3g & 3) * 8;            // shorts

    const unsigned short* xA0 = Xf + (size_t)(r0 +      w * 16 + srow16) * D_K + kgs;
    const unsigned short* xA1 = Xf + (size_t)(r0 + 64 + w * 16 + srow16) * D_K + kgs;
    const unsigned short* xB0 = WT + (size_t)(mb * CP + c0 +      w * 16 + srow16) * D_K + kgs;
    const unsigned short* xB1 = WT + (size_t)(mb * CP + c0 + 64 + w * 16 + srow16) * D_K + kgs;
    unsigned short* dA00 = At + tid * 8;           // subk0 rows 0-63
    unsigned short* dA01 = At + 2048 + tid * 8;    // subk0 rows 64-127
    unsigned short* dA10 = At + 4096 + tid * 8;    // subk1 rows 0-63
    unsigned short* dA11 = At + 6144 + tid * 8;    // subk1 rows 64-127
    unsigned short* dB00 = Bt + tid * 8;
    unsigned short* dB01 = Bt + 2048 + tid * 8;
    unsigned short* dB10 = Bt + 4096 + tid * 8;
    unsigned short* dB11 = Bt + 6144 + tid * 8;

    // fragment read pointers (loop-invariant; subk1 = +8192 bytes)
    auto ldsoff = [&](int row, int kc) {
        return (row >> 1) * 64 + (((((row & 1) << 2) | kc) ^ ((row >> 1) & 7)) * 8);
    };
    const char* aP[4]; const char* bP[4];
#pragma unroll
    for (int i = 0; i < 4; ++i) {
        aP[i] = (const char*)At + 2 * ldsoff(wr * 64 + i * 16 + l15, kg);
        bP[i] = (const char*)Bt + 2 * ldsoff(wc * 64 + i * 16 + l15, kg);
    }

    f32x4 acc[4][4];
#pragma unroll
    for (int i = 0; i < 4; ++i)
#pragma unroll
        for (int j = 0; j < 4; ++j) acc[i][j] = (f32x4){0.f, 0.f, 0.f, 0.f};

#pragma unroll
    for (int t = 0; t < 8; ++t) {
        // stage BK=64 tile t (WAR-safe: trailing barrier of iter t-1 ensures
        // all LDS reads of the previous tile completed)
        gload16(xA0 + t * 64,      dA00);
        gload16(xA1 + t * 64,      dA01);
        gload16(xA0 + t * 64 + 32, dA10);
        gload16(xA1 + t * 64 + 32, dA11);
        gload16(xB0 + t * 64,      dB00);
        gload16(xB1 + t * 64,      dB01);
        gload16(xB0 + t * 64 + 32, dB10);
        gload16(xB1 + t * 64 + 32, dB11);
        __syncthreads();   // drains vmcnt(0): tile t fully in LDS

        f16x8 af[4], bf[4];
        // ---- subk 0 ----
#pragma unroll
        for (int i = 0; i < 4; ++i) af[i] = *reinterpret_cast<const f16x8*>(aP[i]);
#pragma unroll
        for (int j = 0; j < 4; ++j) bf[j] = *reinterpret_cast<const f16x8*>(bP[j]);
#pragma unroll
        for (int i = 0; i < 4; ++i)
#pragma unroll
            for (int j = 0; j < 4; ++j)
                acc[i][j] = __builtin_amdgcn_mfma_f32_16x16x32_f16(af[i], bf[j], acc[i][j], 0, 0, 0);
        // ---- subk 1 ----
#pragma unroll
        for (int i = 0; i < 4; ++i) af[i] = *reinterpret_cast<const f16x8*>(aP[i] + 8192);
#pragma unroll
        for (int j = 0; j < 4; ++j) bf[j] = *reinterpret_cast<const f16x8*>(bP[j] + 8192);
#pragma unroll
        for (int i = 0; i < 4; ++i)
#pragma unroll
            for (int j = 0; j < 4; ++j)
                acc[i][j] = __builtin_amdgcn_mfma_f32_16x16x32_f16(af[i], bf[j], acc[i][j], 0, 0, 0);
        __syncthreads();   // all LDS reads of tile t done before next stage
    }

    // ---------------- epilogue: bias + per-wave top-2 over its 64 cols ----------------
    // wtop overlays dead At (last trailing barrier already passed).
    float4 (*wtop)[2] = reinterpret_cast<float4(*)[2]>(At);

    float bsv[4]; int cg[4];
#pragma unroll
    for (int j = 0; j < 4; ++j) {
        int cc = c0 + wc * 64 + j * 16 + l15;
        cg[j] = cc;
        bsv[j] = (cc < C_N) ? bias[mb * C_N + cc] : -1e30f;
    }
#pragma unroll
    for (int i = 0; i < 4; ++i) {
#pragma unroll
        for (int reg = 0; reg < 4; ++reg) {
            float v1 = acc[i][0][reg] + bsv[0]; int i1 = cg[0];
            float v2 = -1e30f; int i2 = 0x7fffffff;
#pragma unroll
            for (int j = 1; j < 4; ++j) {
                float v = acc[i][j][reg] + bsv[j]; int cc = cg[j];
                if (v > v1 || (v == v1 && cc < i1)) { v2 = v1; i2 = i1; v1 = v; i1 = cc; }
                else if (v > v2 || (v == v2 && cc < i2)) { v2 = v; i2 = cc; }
            }
#pragma unroll
            for (int mask = 1; mask < 16; mask <<= 1) {
                float ov1 = __shfl_xor(v1, mask); int oi1 = __shfl_xor(i1, mask);
                float ov2 = __shfl_xor(v2, mask); int oi2 = __shfl_xor(i2, mask);
                if (ov1 > v1 || (ov1 == v1 && oi1 < i1)) {
                    float nv2 = v1; int ni2 = i1;
                    if (ov2 > nv2 || (ov2 == nv2 && oi2 < ni2)) { nv2 = ov2; ni2 = oi2; }
                    v1 = ov1; i1 = oi1; v2 = nv2; i2 = ni2;
                } else if (ov1 > v2 || (ov1 == v2 && oi1 < i2)) { v2 = ov1; i2 = oi1; }
            }
            if (l15 == 0) {
                int row = wr * 64 + i * 16 + (l >> 4) * 4 + reg;
                wtop[row][wc] = make_float4(v1, __int_as_float(i1), v2, __int_as_float(i2));
            }
        }
    }
    __syncthreads();
    if (tid < 128) {
        float v1 = -1e30f; int i1 = 0x7fffffff;
        float v2 = -1e30f; int i2 = 0x7fffffff;
#pragma unroll
        for (int s = 0; s < 2; ++s) {
            float4 o = wtop[tid][s];
            float ov1 = o.x; int oi1 = __float_as_int(o.y);
            float ov2 = o.z; int oi2 = __float_as_int(o.w);
            if (ov1 > v1 || (ov1 == v1 && oi1 < i1)) {
                float nv2 = v1; int ni2 = i1;
                if (ov2 > nv2 || (ov2 == nv2 && oi2 < ni2)) { nv2 = ov2; ni2 = oi2; }
                v1 = ov1; i1 = oi1; v2 = nv2; i2 = ni2;
            } else if (ov1 > v2 || (ov1 == v2 && oi1 < i2)) { v2 = ov1; i2 = oi1; }
        }
        part[((size_t)mb * B_N + r0 + tid) * 8 + ct] =
            make_float4(v1, __int_as_float(i1), v2, __int_as_float(i2));
    }
}

// -------- merge 8 C-tiles, write approx argmax, flag small-gap rows per model --------

__global__ __launch_bounds__(256) void ve_flag8(const float4* __restrict__ part,
        unsigned int* __restrict__ wout, unsigned int* __restrict__ rlist,
        unsigned int* __restrict__ cnts) {
    int r = blockIdx.x * 256 + threadIdx.x;
#pragma unroll
    for (int m = 0; m < M_N; ++m) {
        float v1 = -1e30f; int i1 = 0x7fffffff;
        float v2 = -1e30f; int i2 = 0x7fffffff;
#pragma unroll
        for (int t = 0; t < 8; ++t) {
            float4 o = part[((size_t)m * B_N + r) * 8 + t];
            float ov1 = o.x; int oi1 = __float_as_int(o.y);
            float ov2 = o.z; int oi2 = __float_as_int(o.w);
            if (ov1 > v1 || (ov1 == v1 && oi1 < i1)) {
                float nv2 = v1; int ni2 = i1;
                if (ov2 > nv2 || (ov2 == nv2 && oi2 < ni2)) { nv2 = ov2; ni2 = oi2; }
                v1 = ov1; i1 = oi1; v2 = nv2; i2 = ni2;
            } else if (ov1 > v2 || (ov1 == v2 && oi1 < i2)) { v2 = ov1; i2 = oi1; }
        }
        wout[m * B_N + r] = (unsigned)i1;
        if (v1 - v2 <= GAP_EPS) {
            unsigned pos = atomicAdd(&cnts[m], 1u);
            rlist[m * B_N + pos] = (unsigned)r;
        }
    }
}

// -------- grouped exact pass: round-1 fp32 kernel over gathered flagged rows --------
// Identical serial-k FMA accumulation to the (numpy-matching) round-1 kernel.

__global__ __launch_bounds__(256) void ve_exact_g(
        const float* __restrict__ x, const float* __restrict__ W,
        const float* __restrict__ bias, const unsigned int* __restrict__ rlist,
        const unsigned int* __restrict__ cnts, float2* __restrict__ part2) {
    __shared__ float xs[32][129];
    __shared__ float wsm[32][128];
    __shared__ int rg[128];
    const int ct = blockIdx.x, m = blockIdx.z;
    const int tid = threadIdx.x;
    const int tx = tid & 15, ty = tid >> 4;
    const int c0 = ct * 128;
    const unsigned nm = cnts[m];

    for (unsigned rb = blockIdx.y; rb * 128 < nm; rb += gridDim.y) {
        __syncthreads();
        if (tid < 128) {
            unsigned idx = rb * 128 + tid;
            rg[tid] = (idx < nm) ? (int)rlist[m * B_N + idx] : 0;
        }
        __syncthreads();

        float acc[8][8];
#pragma unroll
        for (int i = 0; i < 8; i++)
#pragma unroll
            for (int j = 0; j < 8; j++) acc[i][j] = 0.f;

        for (int kt = 0; kt < D_K; kt += 32) {
#pragma unroll
            for (int i = 0; i < 4; i++) {
                int li = tid + i * 256;
                int row = li >> 3, kq = li & 7;
                float4 v = *reinterpret_cast<const float4*>(
                        x + (size_t)rg[row] * D_K + kt + kq * 4);
                int kk = kq * 4;
                xs[kk + 0][row] = v.x; xs[kk + 1][row] = v.y;
                xs[kk + 2][row] = v.z; xs[kk + 3][row] = v.w;
            }
#pragma unroll
            for (int i = 0; i < 4; i++) {
                int li = tid + i * 256;
                int kk = li >> 5, cq = li & 31;
                int c = c0 + cq * 4;
                const float* p = W + ((size_t)(m * D_K + kt + kk)) * C_N + c;
                float4 v;
                if (c + 3 < C_N) v = *reinterpret_cast<const float4*>(p);
                else {
                    v.x = (c + 0 < C_N) ? p[0] : 0.f; v.y = (c + 1 < C_N) ? p[1] : 0.f;
                    v.z = (c + 2 < C_N) ? p[2] : 0.f; v.w = (c + 3 < C_N) ? p[3] : 0.f;
                }
                wsm[kk][cq * 4 + 0] = v.x; wsm[kk][cq * 4 + 1] = v.y;
                wsm[kk][cq * 4 + 2] = v.z; wsm[kk][cq * 4 + 3] = v.w;
            }
            __syncthreads();
            for (int kk = 0; kk < 32; kk++) {
                float a[8], bb[8];
#pragma unroll
                for (int i = 0; i < 8; i++) a[i] = xs[kk][ty + i * 16];
#pragma unroll
                for (int j = 0; j < 8; j++) bb[j] = wsm[kk][tx + j * 16];
#pragma unroll
                for (int i = 0; i < 8; i++)
#pragma unroll
                    for (int j = 0; j < 8; j++) acc[i][j] += a[i] * bb[j];
            }
            __syncthreads();
        }

        const float NEG_INF = -__builtin_huge_valf();
        float bv[8]; int cv[8];
#pragma unroll
        for (int j = 0; j < 8; j++) {
            int c = c0 + tx + j * 16;
            cv[j] = c;
            bv[j] = (c < C_N) ? bias[m * C_N + c] : 0.f;
        }
#pragma unroll
        for (int i = 0; i < 8; i++) {
            float best = NEG_INF; int bidx = 0x7fffffff;
#pragma unroll
            for (int j = 0; j < 8; j++) {
                int c = cv[j];
                float v = (c < C_N) ? (acc[i][j] + bv[j]) : NEG_INF;
                if (v > best || (v == best && c < bidx)) { best = v; bidx = c; }
            }
#pragma unroll
            for (int mask = 1; mask < 16; mask <<= 1) {
                float ov = __shfl_xor(best, mask);
                int oi = __shfl_xor(bidx, mask);
                if (ov > best || (ov == best && oi < bidx)) { best = ov; bidx = oi; }
            }
            unsigned slot = rb * 128 + ty + i * 16;
            if (tx == 0 && slot < nm)
                part2[((size_t)m * B_N + slot) * 8 + ct] = make_float2(best, __int_as_float(bidx));
        }
    }
}

// merge exact per-ct partials -> final argmax for flagged rows
__global__ __launch_bounds__(256) void ve_merge_x(const float2* __restrict__ part2,
        const unsigned int* __restrict__ rlist, const unsigned int* __restrict__ cnts,
        unsigned int* __restrict__ wout) {
    int gid = blockIdx.x * 256 + threadIdx.x;
    int m = gid >> 14, s = gid & (B_N - 1);
    if (s < (int)cnts[m]) {
        const float NEG_INF = -__builtin_huge_valf();
        float best = NEG_INF; int bidx = 0x7fffffff;
#pragma unroll
        for (int ctt = 0; ctt < 8; ctt++) {
            float2 p = part2[((size_t)m * B_N + s) * 8 + ctt];
            int oi = __float_as_int(p.y);
            if (p.x > best || (p.x == best && oi < bidx)) { best = p.x; bidx = oi; }
        }
        wout[m * B_N + rlist[m * B_N + s]] = (unsigned)bidx;
    }
}

__global__ __launch_bounds__(256) void ve_zero_out(float* __restrict__ out, int n4) {
    int i = blockIdx.x * blockDim.x + threadIdx.x;
    const float4 z = make_float4(0.f, 0.f, 0.f, 0.f);
    for (; i < n4; i += gridDim.x * blockDim.x)
        reinterpret_cast<float4*>(out)[i] = z;
}

__global__ __launch_bounds__(256) void ve_vote2(const unsigned int* __restrict__ wout,
        const float* __restrict__ coefs, float* __restrict__ out) {
    int r = blockIdx.x * 256 + threadIdx.x;
#pragma unroll
    for (int m = 0; m < M_N; ++m)
        out[(size_t)r * C_N + wout[m * B_N + r]] += coefs[m] * 0.125f;
}

// ================= fallback: proven round-1 fp32 path =================

#define TM 128
#define TN 128
#define TK 32
#define CT 8

__global__ __launch_bounds__(256) void ve_gemm_argmax_fb(
        const float* __restrict__ x, const float* __restrict__ W,
        const float* __restrict__ bias, float2* __restrict__ part) {
    __shared__ float xs[TK][TM + 1];
    __shared__ float ws[TK][TN];
    const int ct = blockIdx.x, rt = blockIdx.y, m = blockIdx.z;
    const int tid = threadIdx.x;
    const int tx = tid & 15, ty = tid >> 4;
    const int r0 = rt * TM, c0 = ct * TN;
    float acc[8][8];
#pragma unroll
    for (int i = 0; i < 8; i++)
#pragma unroll
        for (int j = 0; j < 8; j++) acc[i][j] = 0.f;
    const float* xbase = x + (size_t)r0 * D_K;
    for (int kt = 0; kt < D_K; kt += TK) {
#pragma unroll
        for (int i = 0; i < 4; i++) {
            int li = tid + i * 256;
            int row = li >> 3, kq = li & 7;
            float4 v = *reinterpret_cast<const float4*>(xbase + (size_t)row * D_K + kt + kq * 4);
            int kk = kq * 4;
            xs[kk + 0][row] = v.x; xs[kk + 1][row] = v.y;
            xs[kk + 2][row] = v.z; xs[kk + 3][row] = v.w;
        }
#pragma unroll
        for (int i = 0; i < 4; i++) {
            int li = tid + i * 256;
            int kk = li >> 5, cq = li & 31;
            int c = c0 + cq * 4;
            const float* p = W + ((size_t)(m * D_K + kt + kk)) * C_N + c;
            float4 v;
            if (c + 3 < C_N) v = *reinterpret_cast<const float4*>(p);
            else {
                v.x = (c + 0 < C_N) ? p[0] : 0.f; v.y = (c + 1 < C_N) ? p[1] : 0.f;
                v.z = (c + 2 < C_N) ? p[2] : 0.f; v.w = (c + 3 < C_N) ? p[3] : 0.f;
            }
            ws[kk][cq * 4 + 0] = v.x; ws[kk][cq * 4 + 1] = v.y;
            ws[kk][cq * 4 + 2] = v.z; ws[kk][cq * 4 + 3] = v.w;
        }
        __syncthreads();
        for (int kk = 0; kk < TK; kk++) {
            float a[8], bb[8];
#pragma unroll
            for (int i = 0; i < 8; i++) a[i] = xs[kk][ty + i * 16];
#pragma unroll
            for (int j = 0; j < 8; j++) bb[j] = ws[kk][tx + j * 16];
#pragma unroll
            for (int i = 0; i < 8; i++)
#pragma unroll
                for (int j = 0; j < 8; j++) acc[i][j] += a[i] * bb[j];
        }
        __syncthreads();
    }
    const float NEG_INF = -__builtin_huge_valf();
    float bv[8]; int cv[8];
#pragma unroll
    for (int j = 0; j < 8; j++) {
        int c = c0 + tx + j * 16;
        cv[j] = c;
        bv[j] = (c < C_N) ? bias[m * C_N + c] : 0.f;
    }
#pragma unroll
    for (int i = 0; i < 8; i++) {
        int r = r0 + ty + i * 16;
        float best = NEG_INF; int bidx = 0x7fffffff;
#pragma unroll
        for (int j = 0; j < 8; j++) {
            int c = cv[j];
            float v = (c < C_N) ? (acc[i][j] + bv[j]) : NEG_INF;
            if (v > best || (v == best && c < bidx)) { best = v; bidx = c; }
        }
#pragma unroll
        for (int mask = 1; mask < 16; mask <<= 1) {
            float ov = __shfl_xor(best, mask);
            int oi = __shfl_xor(bidx, mask);
            if (ov > best || (ov == best && oi < bidx)) { best = ov; bidx = oi; }
        }
        if (tx == 0) part[((size_t)m * B_N + r) * CT + ct] = make_float2(best, __int_as_float(bidx));
    }
}

__global__ __launch_bounds__(256) void ve_vote_fb(const float2* __restrict__ part,
        const float* __restrict__ coefs, float* __restrict__ out) {
    int r = blockIdx.x * blockDim.x + threadIdx.x;
    if (r >= B_N) return;
    const float NEG_INF = -__builtin_huge_valf();
#pragma unroll
    for (int m = 0; m < M_N; m++) {
        float best = NEG_INF; int bidx = 0x7fffffff;
#pragma unroll
        for (int ctt = 0; ctt < CT; ctt++) {
            float2 p = part[((size_t)m * B_N + r) * CT + ctt];
            int oi = __float_as_int(p.y);
            if (p.x > best || (p.x == best && oi < bidx)) { best = p.x; bidx = oi; }
        }
        out[(size_t)r * C_N + bidx] += coefs[m] * 0.125f;
    }
}

// ================= launcher =================

extern "C" void kernel_launch(void* const* d_in, const int* in_sizes, int n_in,
                              void* d_out, int out_size, void* d_ws, size_t ws_size,
                              hipStream_t stream) {
    const float* x     = (const float*)d_in[0];
    const float* W     = (const float*)d_in[1];
    const float* bias  = (const float*)d_in[2];
    const float* coefs = (const float*)d_in[3];
    float* out = (float*)d_out;

    const size_t NEED = (57ull << 20) + 4096;
    if (ws_size >= NEED) {
        char* ws = (char*)d_ws;
        unsigned short* Xf    = (unsigned short*)(ws);                   // 16 MiB
        unsigned short* WT16  = (unsigned short*)(ws + (16ull << 20));   //  8 MiB
        float4*         part  = (float4*)(ws + (24ull << 20));           // 16 MiB
        float2*         part2 = (float2*)(ws + (24ull << 20));           //  8 MiB (reuses part after flag)
        unsigned int*   wout  = (unsigned int*)(ws + (40ull << 20));     // 512 KiB
        unsigned int*   rlist = (unsigned int*)(ws + (40ull << 20) + (512ull << 10)); // 512 KiB
        unsigned int*   cnts  = (unsigned int*)(ws + (41ull << 20));     // 32 B

        ve_conv_x16<<<8192, 256, 0, stream>>>(x, Xf, cnts);
        ve_conv_w16<<<dim3(16, 8, 8), 256, 0, stream>>>(W, WT16);
        ve_gemm16<<<dim3(128, 8, 8), 256, 0, stream>>>(Xf, WT16, bias, part);
        ve_flag8<<<64, 256, 0, stream>>>(part, wout, rlist, cnts);
        ve_exact_g<<<dim3(8, 4, 8), 256, 0, stream>>>(x, W, bias, rlist, cnts, part2);
        ve_merge_x<<<512, 256, 0, stream>>>(part2, rlist, cnts, wout);
        ve_zero_out<<<2048, 256, 0, stream>>>(out, B_N * C_N / 4);
        ve_vote2<<<64, 256, 0, stream>>>(wout, coefs, out);
    } else {
        float2* partf = (float2*)d_ws;
        ve_zero_out<<<2048, 256, 0, stream>>>(out, B_N * C_N / 4);
        dim3 grid(CT, B_N / TM, M_N);
        ve_gemm_argmax_fb<<<grid, 256, 0, stream>>>(x, W, bias, partf);
        ve_vote_fb<<<(B_N + 255) / 256, 256, 0, stream>>>(partf, coefs, out);
    }
}